// Round 5
// baseline (226.708 us; speedup 1.0000x reference)
//
#include <hip/hip_runtime.h>
#include <hip/hip_bf16.h>

#define T_SEQ 2048
#define DM 1024
#define NH 16
#define DKH 64
#define NBATCH 4
#define MROWS (NBATCH*T_SEQ)   // 8192

typedef __attribute__((ext_vector_type(8))) short bf16x8;
typedef __attribute__((ext_vector_type(4))) short bf16x4;
typedef __attribute__((ext_vector_type(4))) float f32x4;
typedef __attribute__((ext_vector_type(4))) unsigned short u16x4;

#define NEG_INF (-__builtin_inff())

#if __has_builtin(__builtin_amdgcn_exp2f)
#define EXP2(x) __builtin_amdgcn_exp2f(x)
#else
#define EXP2(x) exp2f(x)
#endif

static __device__ __forceinline__ unsigned short f2bf(float f){
  union { float f; unsigned u; } v; v.f = f;
  unsigned r = v.u + 0x7fffu + ((v.u >> 16) & 1u);
  return (unsigned short)(r >> 16);
}

// RTNE float->bf16 via HW cvt (compiler fuses pairs into v_cvt_pk_bf16_f32, m240)
static __device__ __forceinline__ unsigned short f2bfc(float f){
  union { __hip_bfloat16 h; unsigned short u; } cv;
  cv.h = __float2bfloat16(f);
  return cv.u;
}

static __device__ __forceinline__ void gload_lds16(const void* g, void* l){
  __builtin_amdgcn_global_load_lds(
      (const __attribute__((address_space(1))) void*)g,
      (__attribute__((address_space(3))) void*)l, 16, 0, 0);
}

// ---------------- convert H (fp32 -> bf16) ----------------
__global__ void convh(const float4* __restrict__ in, u16x4* __restrict__ out, int n4){
  for (int i = blockIdx.x*blockDim.x + threadIdx.x; i < n4; i += gridDim.x*blockDim.x){
    float4 v = in[i];
    u16x4 o;
    o[0] = f2bf(v.x); o[1] = f2bf(v.y); o[2] = f2bf(v.z); o[3] = f2bf(v.w);
    out[i] = o;
  }
}

// ------------- convert + transpose weights (fp32 [k][n] -> bf16 [n][k]) -------------
__global__ void convw(const float* __restrict__ W0, const float* __restrict__ W1,
                      const float* __restrict__ W2, const float* __restrict__ W3,
                      unsigned short* __restrict__ O0, unsigned short* __restrict__ O1,
                      unsigned short* __restrict__ O2, unsigned short* __restrict__ O3)
{
  const float* W = (blockIdx.z==0)?W0:(blockIdx.z==1)?W1:(blockIdx.z==2)?W2:W3;
  unsigned short* O = (blockIdx.z==0)?O0:(blockIdx.z==1)?O1:(blockIdx.z==2)?O2:O3;
  __shared__ float t[32][33];
  const int nx = blockIdx.x*32, kx = blockIdx.y*32;
  const int tx = threadIdx.x, ty = threadIdx.y;
  #pragma unroll
  for (int i = 0; i < 4; ++i)
    t[ty + i*8][tx] = W[(size_t)(kx + ty + i*8)*DM + nx + tx];
  __syncthreads();
  #pragma unroll
  for (int i = 0; i < 4; ++i)
    O[(size_t)(nx + ty + i*8)*DM + kx + tx] = f2bf(t[tx][ty + i*8]);
}

// ---------------- GEMM: C[M][N] = oscale * A[M][K](bf16) * Bt[N][K](bf16)^T ----------------
// 128x128 tile, BK=64, 4 waves (2x2), 16x16x32 bf16 MFMA, global_load_lds staging,
// XOR-swizzled LDS ((row&7) chunk-XOR within 128B rows) for conflict-free ds_read_b128.
template<bool F32OUT>
__global__ __launch_bounds__(256) void gemm_bt(const unsigned short* __restrict__ A,
                                               const unsigned short* __restrict__ Bt,
                                               void* __restrict__ Cp,
                                               int M, int N, int K, float oscale)
{
  __shared__ __attribute__((aligned(16))) unsigned short a_lds[128*64];
  __shared__ __attribute__((aligned(16))) unsigned short b_lds[128*64];
  const int tid = threadIdx.x;
  const int w = tid >> 6, l = tid & 63;
  const int g = l >> 4, lr = l & 15;
  const int wr = w >> 1, wc = w & 1;
  const int m0 = blockIdx.x * 128, n0 = blockIdx.y * 128;
  f32x4 acc[4][4] = {};
  const int nk = K >> 6;
  for (int ks = 0; ks < nk; ++ks){
    __syncthreads();
    const int k0 = ks << 6;
    #pragma unroll
    for (int i = 0; i < 4; ++i){
      int c = (w*4 + i)*64 + l;           // 0..1023, 16B chunks
      int row = c >> 3;
      int gc = (c & 7) ^ (row & 7);       // pre-swizzled global source (m173 pattern)
      gload_lds16(A + (size_t)(m0 + row)*K + (k0 + gc*8), &a_lds[c*8]);
    }
    #pragma unroll
    for (int i = 0; i < 4; ++i){
      int c = (w*4 + i)*64 + l;
      int row = c >> 3;
      int gc = (c & 7) ^ (row & 7);
      gload_lds16(Bt + (size_t)(n0 + row)*K + (k0 + gc*8), &b_lds[c*8]);
    }
    __syncthreads();
    #pragma unroll
    for (int kc = 0; kc < 2; ++kc){
      bf16x8 af[4], bf_[4];
      #pragma unroll
      for (int mt = 0; mt < 4; ++mt){
        int row = wr*64 + mt*16 + lr;
        int off = row*128 + ((kc*64 + g*16) ^ ((row & 7) << 4));
        af[mt] = *(const bf16x8*)((const char*)a_lds + off);
      }
      #pragma unroll
      for (int nt = 0; nt < 4; ++nt){
        int row = wc*64 + nt*16 + lr;
        int off = row*128 + ((kc*64 + g*16) ^ ((row & 7) << 4));
        bf_[nt] = *(const bf16x8*)((const char*)b_lds + off);
      }
      #pragma unroll
      for (int mt = 0; mt < 4; ++mt)
        #pragma unroll
        for (int nt = 0; nt < 4; ++nt)
          acc[mt][nt] = __builtin_amdgcn_mfma_f32_16x16x32_bf16(af[mt], bf_[nt], acc[mt][nt], 0, 0, 0);
    }
  }
  #pragma unroll
  for (int mt = 0; mt < 4; ++mt){
    #pragma unroll
    for (int nt = 0; nt < 4; ++nt){
      const int col = n0 + wc*64 + nt*16 + lr;
      #pragma unroll
      for (int r = 0; r < 4; ++r){
        const int row = m0 + wr*64 + mt*16 + 4*g + r;   // C/D: col=lane&15, row=(lane>>4)*4+r (m89)
        if (F32OUT) ((float*)Cp)[(size_t)row*N + col] = acc[mt][nt][r] * oscale;
        else ((unsigned short*)Cp)[(size_t)row*N + col] = f2bf(acc[mt][nt][r] * oscale);
      }
    }
  }
}

// ---- per-sub-tile softmax (exp2 domain; T13 defer-max THR=8) ----
// s: S^T fragments (scaled by log2e/sqrt(dk) already). Produces pb (P^T bf16
// B-fragments) and updates m/l/acc in place. All indices static (rule 20).
static __device__ __forceinline__ void softmax_tile(
    f32x4 (&s)[4], float& m_run, float& l_run, f32x4 (&acc)[4],
    bf16x4 (&pb)[4], int j0, int qg, int g, bool fullTile)
{
  float p[4][4];
  float tm = NEG_INF;
  if (fullTile){
    #pragma unroll
    for (int kc = 0; kc < 4; ++kc)
      #pragma unroll
      for (int r = 0; r < 4; ++r){
        p[kc][r] = s[kc][r];
        tm = fmaxf(tm, s[kc][r]);
      }
  } else {
    #pragma unroll
    for (int kc = 0; kc < 4; ++kc)
      #pragma unroll
      for (int r = 0; r < 4; ++r){
        int kvg = j0 + kc*16 + 4*g + r;
        float v = (kvg <= qg) ? s[kc][r] : NEG_INF;
        p[kc][r] = v;
        tm = fmaxf(tm, v);
      }
  }
  tm = fmaxf(tm, __shfl_xor(tm, 16));
  tm = fmaxf(tm, __shfl_xor(tm, 32));
  float ps = 0.f;
  if (__all(tm - m_run <= 8.f)){                       // defer: P bounded by 2^8
    const float mm = m_run;
    #pragma unroll
    for (int kc = 0; kc < 4; ++kc)
      #pragma unroll
      for (int r = 0; r < 4; ++r){
        float e = EXP2(p[kc][r] - mm);
        p[kc][r] = e; ps += e;
      }
    ps += __shfl_xor(ps, 16);
    ps += __shfl_xor(ps, 32);
    l_run += ps;
  } else {
    const float m_new = fmaxf(m_run, tm);
    const float fac = EXP2(m_run - m_new);             // first tile: exp2(-inf)=0
    #pragma unroll
    for (int kc = 0; kc < 4; ++kc)
      #pragma unroll
      for (int r = 0; r < 4; ++r){
        float e = EXP2(p[kc][r] - m_new);
        p[kc][r] = e; ps += e;
      }
    ps += __shfl_xor(ps, 16);
    ps += __shfl_xor(ps, 32);
    l_run = l_run * fac + ps;
    m_run = m_new;
    #pragma unroll
    for (int mt = 0; mt < 4; ++mt){
      acc[mt][0] *= fac; acc[mt][1] *= fac; acc[mt][2] *= fac; acc[mt][3] *= fac;
    }
  }
  #pragma unroll
  for (int kc = 0; kc < 4; ++kc){
    bf16x4 t;
    t[0] = (short)f2bfc(p[kc][0]); t[1] = (short)f2bfc(p[kc][1]);
    t[2] = (short)f2bfc(p[kc][2]); t[3] = (short)f2bfc(p[kc][3]);
    pb[kc] = t;
  }
}

// ---------------- causal flash attention ----------------
// Grid: 512 linear blocks; decode L -> xcd=L&7, idx=L>>3, bh=xcd*8+(idx&7),
// qblk=7-(idx>>3): qblk-major heavy-first within each XCD, K/V L2-resident.
// Block: 8 waves x 512 thr; QBLK=256 — wave w owns TWO 16-row q-sub-tiles
// (q0+w*16 and q0+128+w*16): two independent softmax chains give 2x ILP, and
// K/V LDS fragments are read ONCE and shared by both. KVBLK=64, double-buffered,
// prefetch before compute, one barrier per tile.
// Swapped QK^T: S^T = mfma(K,Q); Q pre-scaled by log2e/sqrt(dk) (exp2-domain).
// PV: O^T = V^T @ P^T via mfma_16x16x16bf16_1k; Vt[n][t] pre-transposed by GEMM.
__global__ __launch_bounds__(512) void attn_kernel(const unsigned short* __restrict__ Qg,
                                                   const unsigned short* __restrict__ Kg,
                                                   const unsigned short* __restrict__ Vt,
                                                   unsigned short* __restrict__ Og)
{
  __shared__ __attribute__((aligned(16))) unsigned short k_lds[2][64*64];
  __shared__ __attribute__((aligned(16))) unsigned short v_lds[2][64*64];
  const int tid = threadIdx.x;
  const int w = tid >> 6, l = tid & 63;
  const int g = l >> 4, lr = l & 15;
  const int L = blockIdx.x;
  const int xcd = L & 7, idx = L >> 3;
  const int bh = xcd*8 + (idx & 7);
  const int qblk = 7 - (idx >> 3);                     // heavy-first
  const int b = bh >> 4, h = bh & 15;
  const int q0 = qblk * 256;
  const int qlo0 = q0 + w*16,        qhi0 = qlo0 + 15, qg0 = qlo0 + lr;
  const int qlo1 = q0 + 128 + w*16,  qhi1 = qlo1 + 15, qg1 = qlo1 + lr;
  const size_t rowQ0 = (size_t)(b*T_SEQ + qg0)*DM + h*DKH;
  const size_t rowQ1 = (size_t)(b*T_SEQ + qg1)*DM + h*DKH;
  bf16x8 qf0[2], qf1[2];
  qf0[0] = *(const bf16x8*)(Qg + rowQ0 + g*8);
  qf0[1] = *(const bf16x8*)(Qg + rowQ0 + 32 + g*8);
  qf1[0] = *(const bf16x8*)(Qg + rowQ1 + g*8);
  qf1[1] = *(const bf16x8*)(Qg + rowQ1 + 32 + g*8);
  float m_run0 = NEG_INF, l_run0 = 0.f, m_run1 = NEG_INF, l_run1 = 0.f;
  f32x4 acc0[4] = {}, acc1[4] = {};                    // O^T[dk=16mt+4g+r][q=lr]
  const int ntiles = 4*qblk + 4;
  const size_t baseK = (size_t)(b*T_SEQ)*DM + h*DKH;            // K rows [t][n]
  const size_t baseV = (size_t)(h*DKH)*MROWS + (size_t)b*T_SEQ; // Vt rows [n][t]

  // staging: 512 thr x one 16B chunk each for K and V
  const int c0 = tid;
  const int r0 = c0 >> 3, gc0 = (c0 & 7) ^ (r0 & 7);

  auto STAGE = [&](int jt, int buf){
    const int j0s = jt * 64;
    gload_lds16(Kg + baseK + (size_t)(j0s + r0)*DM + gc0*8, &k_lds[buf][c0*8]);
    gload_lds16(Vt + baseV + (size_t)r0*MROWS + j0s + gc0*8, &v_lds[buf][c0*8]);
  };

  STAGE(0, 0);
  __syncthreads();                                      // drains vmcnt -> buf0 ready

  for (int jt = 0; jt < ntiles; ++jt){
    const int cur = jt & 1;
    if (jt + 1 < ntiles) STAGE(jt + 1, cur ^ 1);        // prefetch (hidden under compute)
    const int j0 = jt * 64;

    if (j0 <= qhi1){                                    // sub-tile 1 active (upper rows)
      const bool do0 = (j0 <= qhi0);                    // sub-tile 0 active (wave-uniform)
      // QK^T: K fragment read once, used by both chains
      f32x4 s0[4] = {}, s1[4] = {};
      #pragma unroll
      for (int kc = 0; kc < 4; ++kc){
        const int row = kc*16 + lr;
        #pragma unroll
        for (int c2 = 0; c2 < 2; ++c2){
          const int off = row*128 + ((c2*64 + g*16) ^ ((row & 7) << 4));
          bf16x8 kf = *(const bf16x8*)((const char*)k_lds[cur] + off);
          if (do0) s0[kc] = __builtin_amdgcn_mfma_f32_16x16x32_bf16(kf, qf0[c2], s0[kc], 0, 0, 0);
          s1[kc] = __builtin_amdgcn_mfma_f32_16x16x32_bf16(kf, qf1[c2], s1[kc], 0, 0, 0);
        }
      }
      bf16x4 pb0[4], pb1[4];
      if (do0) softmax_tile(s0, m_run0, l_run0, acc0, pb0, j0, qg0, g, (j0 + 63) <= qlo0);
      softmax_tile(s1, m_run1, l_run1, acc1, pb1, j0, qg1, g, (j0 + 63) <= qlo1);
      // PV: V fragment read once, used by both chains
      #pragma unroll
      for (int mt = 0; mt < 4; ++mt){
        const int vrow = mt*16 + lr;
        #pragma unroll
        for (int kc = 0; kc < 4; ++kc){
          const int voff = vrow*128 + ((((kc<<1) + (g>>1)) ^ (vrow & 7)) << 4) + ((g & 1) << 3);
          bf16x4 vf = *(const bf16x4*)((const char*)v_lds[cur] + voff);
          if (do0) acc0[mt] = __builtin_amdgcn_mfma_f32_16x16x16bf16_1k(vf, pb0[kc], acc0[mt], 0, 0, 0);
          acc1[mt] = __builtin_amdgcn_mfma_f32_16x16x16bf16_1k(vf, pb1[kc], acc1[mt], 0, 0, 0);
        }
      }
    }
    __syncthreads();                                    // buf[cur] free; prefetch drained
  }
  // epilogue: normalize, pack pairs, store bf16 (both sub-tiles)
  {
    const float inv = 1.f / l_run0;
    const size_t rowO = (size_t)(b*T_SEQ + qg0)*DM + h*DKH;
    #pragma unroll
    for (int mt = 0; mt < 4; ++mt){
      unsigned u0 = (unsigned)f2bf(acc0[mt][0]*inv) | ((unsigned)f2bf(acc0[mt][1]*inv) << 16);
      unsigned u1 = (unsigned)f2bf(acc0[mt][2]*inv) | ((unsigned)f2bf(acc0[mt][3]*inv) << 16);
      *(unsigned*)(Og + rowO + mt*16 + 4*g)     = u0;
      *(unsigned*)(Og + rowO + mt*16 + 4*g + 2) = u1;
    }
  }
  {
    const float inv = 1.f / l_run1;
    const size_t rowO = (size_t)(b*T_SEQ + qg1)*DM + h*DKH;
    #pragma unroll
    for (int mt = 0; mt < 4; ++mt){
      unsigned u0 = (unsigned)f2bf(acc1[mt][0]*inv) | ((unsigned)f2bf(acc1[mt][1]*inv) << 16);
      unsigned u1 = (unsigned)f2bf(acc1[mt][2]*inv) | ((unsigned)f2bf(acc1[mt][3]*inv) << 16);
      *(unsigned*)(Og + rowO + mt*16 + 4*g)     = u0;
      *(unsigned*)(Og + rowO + mt*16 + 4*g + 2) = u1;
    }
  }
}

// ---------------- launch ----------------
extern "C" void kernel_launch(void* const* d_in, const int* in_sizes, int n_in,
                              void* d_out, int out_size, void* d_ws, size_t ws_size,
                              hipStream_t stream)
{
  (void)in_sizes; (void)n_in; (void)out_size; (void)ws_size;
  const float* H  = (const float*)d_in[0];
  const float* Wq = (const float*)d_in[1];
  const float* Wk = (const float*)d_in[2];
  const float* Wv = (const float*)d_in[3];
  const float* Wo = (const float*)d_in[4];
  char* ws = (char*)d_ws;
  // ws layout (bytes): Hb 16MB | Wq/Wk/Wv/Wo^T bf16 2MB each | Q,K 16MB each | Vt 16MB | Ab 16MB = 88MB
  unsigned short* Hb  = (unsigned short*)(ws);
  unsigned short* Wqt = (unsigned short*)(ws + 16777216);
  unsigned short* Wkt = (unsigned short*)(ws + 18874368);
  unsigned short* Wvt = (unsigned short*)(ws + 20971520);
  unsigned short* Wot = (unsigned short*)(ws + 23068672);
  unsigned short* Qb  = (unsigned short*)(ws + 25165824);
  unsigned short* Kb  = (unsigned short*)(ws + 41943040);
  unsigned short* Vtb = (unsigned short*)(ws + 58720256);
  unsigned short* Ab  = (unsigned short*)(ws + 75497472);

  convh<<<2048, 256, 0, stream>>>((const float4*)H, (u16x4*)Hb, MROWS*DM/4);
  convw<<<dim3(32,32,4), dim3(32,8), 0, stream>>>(Wq, Wk, Wv, Wo, Wqt, Wkt, Wvt, Wot);
  // Q pre-scaled by log2e/sqrt(64) for exp2-domain softmax
  gemm_bt<false><<<dim3(64,8), 256, 0, stream>>>(Hb, Wqt, Qb, MROWS, DM, DM, 0.18033688f);
  gemm_bt<false><<<dim3(64,8), 256, 0, stream>>>(Hb, Wkt, Kb, MROWS, DM, DM, 1.0f);
  // V^T = (H Wv)^T computed directly: C[n][t] = sum_k Wvt[n][k] * Hb[t][k]
  gemm_bt<false><<<dim3(8,64), 256, 0, stream>>>(Wvt, Hb, Vtb, DM, MROWS, DM, 1.0f);
  attn_kernel<<<dim3(512), 512, 0, stream>>>(Qb, Kb, Vtb, Ab);
  gemm_bt<true><<<dim3(64,8), 256, 0, stream>>>(Ab, Wot, d_out, MROWS, DM, DM, 1.0f);
}

// Round 6
// 210.366 us; speedup vs baseline: 1.0777x; 1.0777x over previous
//
#include <hip/hip_runtime.h>
#include <hip/hip_bf16.h>

#define T_SEQ 2048
#define DM 1024
#define NH 16
#define DKH 64
#define NBATCH 4
#define MROWS (NBATCH*T_SEQ)   // 8192

typedef __attribute__((ext_vector_type(8))) short bf16x8;
typedef __attribute__((ext_vector_type(4))) short bf16x4;
typedef __attribute__((ext_vector_type(4))) float f32x4;
typedef __attribute__((ext_vector_type(4))) unsigned short u16x4;

#define NEG_INF (-__builtin_inff())

#if __has_builtin(__builtin_amdgcn_exp2f)
#define EXP2(x) __builtin_amdgcn_exp2f(x)
#else
#define EXP2(x) exp2f(x)
#endif

static __device__ __forceinline__ unsigned short f2bf(float f){
  union { float f; unsigned u; } v; v.f = f;
  unsigned r = v.u + 0x7fffu + ((v.u >> 16) & 1u);
  return (unsigned short)(r >> 16);
}

// RTNE float->bf16 via HW cvt (compiler fuses pairs into v_cvt_pk_bf16_f32, m240)
static __device__ __forceinline__ unsigned short f2bfc(float f){
  union { __hip_bfloat16 h; unsigned short u; } cv;
  cv.h = __float2bfloat16(f);
  return cv.u;
}

static __device__ __forceinline__ void gload_lds16(const void* g, void* l){
  __builtin_amdgcn_global_load_lds(
      (const __attribute__((address_space(1))) void*)g,
      (__attribute__((address_space(3))) void*)l, 16, 0, 0);
}

// ---------------- convert H (fp32 -> bf16) ----------------
__global__ void convh(const float4* __restrict__ in, u16x4* __restrict__ out, int n4){
  for (int i = blockIdx.x*blockDim.x + threadIdx.x; i < n4; i += gridDim.x*blockDim.x){
    float4 v = in[i];
    u16x4 o;
    o[0] = f2bf(v.x); o[1] = f2bf(v.y); o[2] = f2bf(v.z); o[3] = f2bf(v.w);
    out[i] = o;
  }
}

// ------------- convert + transpose weights (fp32 [k][n] -> bf16 [n][k]) -------------
__global__ void convw(const float* __restrict__ W0, const float* __restrict__ W1,
                      const float* __restrict__ W2, const float* __restrict__ W3,
                      unsigned short* __restrict__ O0, unsigned short* __restrict__ O1,
                      unsigned short* __restrict__ O2, unsigned short* __restrict__ O3)
{
  const float* W = (blockIdx.z==0)?W0:(blockIdx.z==1)?W1:(blockIdx.z==2)?W2:W3;
  unsigned short* O = (blockIdx.z==0)?O0:(blockIdx.z==1)?O1:(blockIdx.z==2)?O2:O3;
  __shared__ float t[32][33];
  const int nx = blockIdx.x*32, kx = blockIdx.y*32;
  const int tx = threadIdx.x, ty = threadIdx.y;
  #pragma unroll
  for (int i = 0; i < 4; ++i)
    t[ty + i*8][tx] = W[(size_t)(kx + ty + i*8)*DM + nx + tx];
  __syncthreads();
  #pragma unroll
  for (int i = 0; i < 4; ++i)
    O[(size_t)(nx + ty + i*8)*DM + kx + tx] = f2bf(t[tx][ty + i*8]);
}

// ---------------- GEMM: C[M][N] = oscale * A[M][K](bf16) * Bt[N][K](bf16)^T ----------------
// 128x128 tile, BK=64, 4 waves (2x2), 16x16x32 bf16 MFMA, global_load_lds staging,
// XOR-swizzled LDS ((row&7) chunk-XOR within 128B rows) for conflict-free ds_read_b128.
template<bool F32OUT>
__global__ __launch_bounds__(256) void gemm_bt(const unsigned short* __restrict__ A,
                                               const unsigned short* __restrict__ Bt,
                                               void* __restrict__ Cp,
                                               int M, int N, int K, float oscale)
{
  __shared__ __attribute__((aligned(16))) unsigned short a_lds[128*64];
  __shared__ __attribute__((aligned(16))) unsigned short b_lds[128*64];
  const int tid = threadIdx.x;
  const int w = tid >> 6, l = tid & 63;
  const int g = l >> 4, lr = l & 15;
  const int wr = w >> 1, wc = w & 1;
  const int m0 = blockIdx.x * 128, n0 = blockIdx.y * 128;
  f32x4 acc[4][4] = {};
  const int nk = K >> 6;
  for (int ks = 0; ks < nk; ++ks){
    __syncthreads();
    const int k0 = ks << 6;
    #pragma unroll
    for (int i = 0; i < 4; ++i){
      int c = (w*4 + i)*64 + l;           // 0..1023, 16B chunks
      int row = c >> 3;
      int gc = (c & 7) ^ (row & 7);       // pre-swizzled global source (m173 pattern)
      gload_lds16(A + (size_t)(m0 + row)*K + (k0 + gc*8), &a_lds[c*8]);
    }
    #pragma unroll
    for (int i = 0; i < 4; ++i){
      int c = (w*4 + i)*64 + l;
      int row = c >> 3;
      int gc = (c & 7) ^ (row & 7);
      gload_lds16(Bt + (size_t)(n0 + row)*K + (k0 + gc*8), &b_lds[c*8]);
    }
    __syncthreads();
    #pragma unroll
    for (int kc = 0; kc < 2; ++kc){
      bf16x8 af[4], bf_[4];
      #pragma unroll
      for (int mt = 0; mt < 4; ++mt){
        int row = wr*64 + mt*16 + lr;
        int off = row*128 + ((kc*64 + g*16) ^ ((row & 7) << 4));
        af[mt] = *(const bf16x8*)((const char*)a_lds + off);
      }
      #pragma unroll
      for (int nt = 0; nt < 4; ++nt){
        int row = wc*64 + nt*16 + lr;
        int off = row*128 + ((kc*64 + g*16) ^ ((row & 7) << 4));
        bf_[nt] = *(const bf16x8*)((const char*)b_lds + off);
      }
      #pragma unroll
      for (int mt = 0; mt < 4; ++mt)
        #pragma unroll
        for (int nt = 0; nt < 4; ++nt)
          acc[mt][nt] = __builtin_amdgcn_mfma_f32_16x16x32_bf16(af[mt], bf_[nt], acc[mt][nt], 0, 0, 0);
    }
  }
  #pragma unroll
  for (int mt = 0; mt < 4; ++mt){
    #pragma unroll
    for (int nt = 0; nt < 4; ++nt){
      const int col = n0 + wc*64 + nt*16 + lr;
      #pragma unroll
      for (int r = 0; r < 4; ++r){
        const int row = m0 + wr*64 + mt*16 + 4*g + r;   // C/D: col=lane&15, row=(lane>>4)*4+r (m89)
        if (F32OUT) ((float*)Cp)[(size_t)row*N + col] = acc[mt][nt][r] * oscale;
        else ((unsigned short*)Cp)[(size_t)row*N + col] = f2bf(acc[mt][nt][r] * oscale);
      }
    }
  }
}

// ---- per-tile softmax (exp2 domain; T13 defer-max THR=8) ----
// s: S^T fragments (pre-scaled by log2e/sqrt(dk)). Produces pb (P^T bf16
// B-fragments) and updates m/l/acc in place. All indices static (rule 20).
static __device__ __forceinline__ void softmax_tile(
    f32x4 (&s)[4], float& m_run, float& l_run, f32x4 (&acc)[4],
    bf16x4 (&pb)[4], int j0, int qg, int g, bool fullTile)
{
  float p[4][4];
  float tm = NEG_INF;
  if (fullTile){
    #pragma unroll
    for (int kc = 0; kc < 4; ++kc)
      #pragma unroll
      for (int r = 0; r < 4; ++r){
        p[kc][r] = s[kc][r];
        tm = fmaxf(tm, s[kc][r]);
      }
  } else {
    #pragma unroll
    for (int kc = 0; kc < 4; ++kc)
      #pragma unroll
      for (int r = 0; r < 4; ++r){
        int kvg = j0 + kc*16 + 4*g + r;
        float v = (kvg <= qg) ? s[kc][r] : NEG_INF;
        p[kc][r] = v;
        tm = fmaxf(tm, v);
      }
  }
  tm = fmaxf(tm, __shfl_xor(tm, 16));
  tm = fmaxf(tm, __shfl_xor(tm, 32));
  float ps = 0.f;
  if (__all(tm - m_run <= 8.f)){                       // defer: P bounded by 2^8
    const float mm = m_run;
    #pragma unroll
    for (int kc = 0; kc < 4; ++kc)
      #pragma unroll
      for (int r = 0; r < 4; ++r){
        float e = EXP2(p[kc][r] - mm);
        p[kc][r] = e; ps += e;
      }
    ps += __shfl_xor(ps, 16);
    ps += __shfl_xor(ps, 32);
    l_run += ps;
  } else {
    const float m_new = fmaxf(m_run, tm);
    const float fac = EXP2(m_run - m_new);             // first tile: exp2(-inf)=0
    #pragma unroll
    for (int kc = 0; kc < 4; ++kc)
      #pragma unroll
      for (int r = 0; r < 4; ++r){
        float e = EXP2(p[kc][r] - m_new);
        p[kc][r] = e; ps += e;
      }
    ps += __shfl_xor(ps, 16);
    ps += __shfl_xor(ps, 32);
    l_run = l_run * fac + ps;
    m_run = m_new;
    #pragma unroll
    for (int mt = 0; mt < 4; ++mt){
      acc[mt][0] *= fac; acc[mt][1] *= fac; acc[mt][2] *= fac; acc[mt][3] *= fac;
    }
  }
  #pragma unroll
  for (int kc = 0; kc < 4; ++kc){
    bf16x4 t;
    t[0] = (short)f2bfc(p[kc][0]); t[1] = (short)f2bfc(p[kc][1]);
    t[2] = (short)f2bfc(p[kc][2]); t[3] = (short)f2bfc(p[kc][3]);
    pb[kc] = t;
  }
}

// ---------------- causal flash attention ----------------
// R4 structure (best measured): grid 1024 linear; decode L -> (xcd=L&7,
// bh=xcd*8+(idx>>4), qblk=15-(idx&15)) — XCD-grouped K/V L2-residency +
// heavy-first. Block: 8 waves x 512 thr; QBLK=128 (wave w owns q-rows
// q0+w*16..+15, ONE chain per wave), KVBLK=64, double-buffered prefetch,
// one barrier per tile. Swapped QK^T (S^T = mfma(K,Q)); Q pre-scaled by
// log2e/sqrt(dk) (exp2-domain). PV: O^T = V^T @ P^T via mfma_16x16x16bf16_1k;
// Vt[n][t] pre-transposed by GEMM.
__global__ __launch_bounds__(512) void attn_kernel(const unsigned short* __restrict__ Qg,
                                                   const unsigned short* __restrict__ Kg,
                                                   const unsigned short* __restrict__ Vt,
                                                   unsigned short* __restrict__ Og)
{
  __shared__ __attribute__((aligned(16))) unsigned short k_lds[2][64*64];
  __shared__ __attribute__((aligned(16))) unsigned short v_lds[2][64*64];
  const int tid = threadIdx.x;
  const int w = tid >> 6, l = tid & 63;
  const int g = l >> 4, lr = l & 15;
  const int L = blockIdx.x;
  const int xcd = L & 7, idx = L >> 3;
  const int bh = xcd*8 + (idx >> 4);
  const int qblk = 15 - (idx & 15);                    // heavy-first
  const int b = bh >> 4, h = bh & 15;
  const int q0 = qblk * 128;
  const int qlo = q0 + w*16;
  const int qhi = qlo + 15;
  const int qg = qlo + lr;                             // this lane's q row
  const size_t rowQ = (size_t)(b*T_SEQ + qg)*DM + h*DKH;
  bf16x8 qf[2];
  qf[0] = *(const bf16x8*)(Qg + rowQ + g*8);
  qf[1] = *(const bf16x8*)(Qg + rowQ + 32 + g*8);
  float m_run = NEG_INF, l_run = 0.f;
  f32x4 acc[4] = {};                                    // acc[mt]: O^T[dk=16mt+4g+r][q=lr]
  const int ntiles = 2*qblk + 2;
  const size_t baseK = (size_t)(b*T_SEQ)*DM + h*DKH;            // K rows [t][n]
  const size_t baseV = (size_t)(h*DKH)*MROWS + (size_t)b*T_SEQ; // Vt rows [n][t]

  // per-thread staging geometry (loop-invariant): 512 thr x 1 16B chunk each
  const int c0 = tid;                                   // 16B chunk id 0..511
  const int r0 = c0 >> 3, gc0 = (c0 & 7) ^ (r0 & 7);

  auto STAGE = [&](int jt, int buf){
    const int j0s = jt * 64;
    gload_lds16(Kg + baseK + (size_t)(j0s + r0)*DM + gc0*8, &k_lds[buf][c0*8]);
    gload_lds16(Vt + baseV + (size_t)r0*MROWS + j0s + gc0*8, &v_lds[buf][c0*8]);
  };

  STAGE(0, 0);
  __syncthreads();                                      // drains vmcnt -> buf0 ready

  for (int jt = 0; jt < ntiles; ++jt){
    const int cur = jt & 1;
    if (jt + 1 < ntiles) STAGE(jt + 1, cur ^ 1);        // prefetch next tile (hidden under compute)
    const int j0 = jt * 64;

    if (j0 <= qhi){                                     // skip fully-masked wave-tiles (wave-uniform)
      // QK^T (swapped): S^T tiles, kv=16 each
      f32x4 s[4];
      #pragma unroll
      for (int kc = 0; kc < 4; ++kc){
        f32x4 z = {};
        #pragma unroll
        for (int c2 = 0; c2 < 2; ++c2){
          int row = kc*16 + lr;
          int off = row*128 + ((c2*64 + g*16) ^ ((row & 7) << 4));
          bf16x8 kf = *(const bf16x8*)((const char*)k_lds[cur] + off);
          z = __builtin_amdgcn_mfma_f32_16x16x32_bf16(kf, qf[c2], z, 0, 0, 0);
        }
        s[kc] = z;
      }
      bf16x4 pb[4];
      softmax_tile(s, m_run, l_run, acc, pb, j0, qg, g, (j0 + 63) <= qlo);
      // PV: A-frag = V^T[dk=mt*16+lr][kv=kc*16+4g..+3], swizzled 8B read from v_lds
      #pragma unroll
      for (int mt = 0; mt < 4; ++mt){
        const int vrow = mt*16 + lr;
        #pragma unroll
        for (int kc = 0; kc < 4; ++kc){
          const int voff = vrow*128 + ((((kc<<1) + (g>>1)) ^ (vrow & 7)) << 4) + ((g & 1) << 3);
          bf16x4 vf = *(const bf16x4*)((const char*)v_lds[cur] + voff);
          acc[mt] = __builtin_amdgcn_mfma_f32_16x16x16bf16_1k(vf, pb[kc], acc[mt], 0, 0, 0);
        }
      }
    }
    __syncthreads();                                    // all waves done with buf[cur]; prefetch drained
  }
  // epilogue: normalize, pack pairs (cvt_pk), store bf16
  const float inv = 1.f / l_run;
  const size_t rowO = (size_t)(b*T_SEQ + qg)*DM + h*DKH;
  #pragma unroll
  for (int mt = 0; mt < 4; ++mt){
    unsigned u0 = (unsigned)f2bfc(acc[mt][0]*inv) | ((unsigned)f2bfc(acc[mt][1]*inv) << 16);
    unsigned u1 = (unsigned)f2bfc(acc[mt][2]*inv) | ((unsigned)f2bfc(acc[mt][3]*inv) << 16);
    *(unsigned*)(Og + rowO + mt*16 + 4*g)     = u0;
    *(unsigned*)(Og + rowO + mt*16 + 4*g + 2) = u1;
  }
}

// ---------------- launch ----------------
extern "C" void kernel_launch(void* const* d_in, const int* in_sizes, int n_in,
                              void* d_out, int out_size, void* d_ws, size_t ws_size,
                              hipStream_t stream)
{
  (void)in_sizes; (void)n_in; (void)out_size; (void)ws_size;
  const float* H  = (const float*)d_in[0];
  const float* Wq = (const float*)d_in[1];
  const float* Wk = (const float*)d_in[2];
  const float* Wv = (const float*)d_in[3];
  const float* Wo = (const float*)d_in[4];
  char* ws = (char*)d_ws;
  // ws layout (bytes): Hb 16MB | Wq/Wk/Wv/Wo^T bf16 2MB each | Q,K 16MB each | Vt 16MB | Ab 16MB = 88MB
  unsigned short* Hb  = (unsigned short*)(ws);
  unsigned short* Wqt = (unsigned short*)(ws + 16777216);
  unsigned short* Wkt = (unsigned short*)(ws + 18874368);
  unsigned short* Wvt = (unsigned short*)(ws + 20971520);
  unsigned short* Wot = (unsigned short*)(ws + 23068672);
  unsigned short* Qb  = (unsigned short*)(ws + 25165824);
  unsigned short* Kb  = (unsigned short*)(ws + 41943040);
  unsigned short* Vtb = (unsigned short*)(ws + 58720256);
  unsigned short* Ab  = (unsigned short*)(ws + 75497472);

  convh<<<2048, 256, 0, stream>>>((const float4*)H, (u16x4*)Hb, MROWS*DM/4);
  convw<<<dim3(32,32,4), dim3(32,8), 0, stream>>>(Wq, Wk, Wv, Wo, Wqt, Wkt, Wvt, Wot);
  // Q pre-scaled by log2e/sqrt(64) for exp2-domain softmax
  gemm_bt<false><<<dim3(64,8), 256, 0, stream>>>(Hb, Wqt, Qb, MROWS, DM, DM, 0.18033688f);
  gemm_bt<false><<<dim3(64,8), 256, 0, stream>>>(Hb, Wkt, Kb, MROWS, DM, DM, 1.0f);
  // V^T = (H Wv)^T computed directly: C[n][t] = sum_k Wvt[n][k] * Hb[t][k]
  gemm_bt<false><<<dim3(8,64), 256, 0, stream>>>(Wvt, Hb, Vtb, DM, MROWS, DM, 1.0f);
  attn_kernel<<<dim3(1024), 512, 0, stream>>>(Qb, Kb, Vtb, Ab);
  gemm_bt<true><<<dim3(64,8), 256, 0, stream>>>(Ab, Wot, d_out, MROWS, DM, DM, 1.0f);
}

// Round 7
// 192.962 us; speedup vs baseline: 1.1749x; 1.0902x over previous
//
#include <hip/hip_runtime.h>
#include <hip/hip_bf16.h>

#define T_SEQ 2048
#define DM 1024
#define NH 16
#define DKH 64
#define NBATCH 4
#define MROWS (NBATCH*T_SEQ)   // 8192

typedef __attribute__((ext_vector_type(8))) short bf16x8;
typedef __attribute__((ext_vector_type(4))) short bf16x4;
typedef __attribute__((ext_vector_type(4))) float f32x4;
typedef __attribute__((ext_vector_type(4))) unsigned short u16x4;

#define NEG_INF (-__builtin_inff())

#if __has_builtin(__builtin_amdgcn_exp2f)
#define EXP2(x) __builtin_amdgcn_exp2f(x)
#else
#define EXP2(x) exp2f(x)
#endif

static __device__ __forceinline__ unsigned short f2bf(float f){
  union { float f; unsigned u; } v; v.f = f;
  unsigned r = v.u + 0x7fffu + ((v.u >> 16) & 1u);
  return (unsigned short)(r >> 16);
}

// RTNE float->bf16 via HW cvt (compiler fuses pairs into v_cvt_pk_bf16_f32, m240)
static __device__ __forceinline__ unsigned short f2bfc(float f){
  union { __hip_bfloat16 h; unsigned short u; } cv;
  cv.h = __float2bfloat16(f);
  return cv.u;
}

static __device__ __forceinline__ void gload_lds16(const void* g, void* l){
  __builtin_amdgcn_global_load_lds(
      (const __attribute__((address_space(1))) void*)g,
      (__attribute__((address_space(3))) void*)l, 16, 0, 0);
}

// ---------------- convert H (fp32 -> bf16) ----------------
__global__ void convh(const float4* __restrict__ in, u16x4* __restrict__ out, int n4){
  for (int i = blockIdx.x*blockDim.x + threadIdx.x; i < n4; i += gridDim.x*blockDim.x){
    float4 v = in[i];
    u16x4 o;
    o[0] = f2bf(v.x); o[1] = f2bf(v.y); o[2] = f2bf(v.z); o[3] = f2bf(v.w);
    out[i] = o;
  }
}

// ------------- convert + transpose weights (fp32 [k][n] -> bf16 [n][k]) -------------
__global__ void convw(const float* __restrict__ W0, const float* __restrict__ W1,
                      const float* __restrict__ W2, const float* __restrict__ W3,
                      unsigned short* __restrict__ O0, unsigned short* __restrict__ O1,
                      unsigned short* __restrict__ O2, unsigned short* __restrict__ O3)
{
  const float* W = (blockIdx.z==0)?W0:(blockIdx.z==1)?W1:(blockIdx.z==2)?W2:W3;
  unsigned short* O = (blockIdx.z==0)?O0:(blockIdx.z==1)?O1:(blockIdx.z==2)?O2:O3;
  __shared__ float t[32][33];
  const int nx = blockIdx.x*32, kx = blockIdx.y*32;
  const int tx = threadIdx.x, ty = threadIdx.y;
  #pragma unroll
  for (int i = 0; i < 4; ++i)
    t[ty + i*8][tx] = W[(size_t)(kx + ty + i*8)*DM + nx + tx];
  __syncthreads();
  #pragma unroll
  for (int i = 0; i < 4; ++i)
    O[(size_t)(nx + ty + i*8)*DM + kx + tx] = f2bf(t[tx][ty + i*8]);
}

// ---------------- GEMM: C[M][N] = oscale * A[M][K](bf16) * Bt[N][K](bf16)^T ----------------
// 128x128 tile, BK=64, 4 waves (2x2), 16x16x32 bf16 MFMA, global_load_lds staging,
// XOR-swizzled LDS ((row&7) chunk-XOR within 128B rows) for conflict-free ds_read_b128.
template<bool F32OUT>
__global__ __launch_bounds__(256) void gemm_bt(const unsigned short* __restrict__ A,
                                               const unsigned short* __restrict__ Bt,
                                               void* __restrict__ Cp,
                                               int M, int N, int K, float oscale)
{
  __shared__ __attribute__((aligned(16))) unsigned short a_lds[128*64];
  __shared__ __attribute__((aligned(16))) unsigned short b_lds[128*64];
  const int tid = threadIdx.x;
  const int w = tid >> 6, l = tid & 63;
  const int g = l >> 4, lr = l & 15;
  const int wr = w >> 1, wc = w & 1;
  const int m0 = blockIdx.x * 128, n0 = blockIdx.y * 128;
  f32x4 acc[4][4] = {};
  const int nk = K >> 6;
  for (int ks = 0; ks < nk; ++ks){
    __syncthreads();
    const int k0 = ks << 6;
    #pragma unroll
    for (int i = 0; i < 4; ++i){
      int c = (w*4 + i)*64 + l;           // 0..1023, 16B chunks
      int row = c >> 3;
      int gc = (c & 7) ^ (row & 7);       // pre-swizzled global source (m173 pattern)
      gload_lds16(A + (size_t)(m0 + row)*K + (k0 + gc*8), &a_lds[c*8]);
    }
    #pragma unroll
    for (int i = 0; i < 4; ++i){
      int c = (w*4 + i)*64 + l;
      int row = c >> 3;
      int gc = (c & 7) ^ (row & 7);
      gload_lds16(Bt + (size_t)(n0 + row)*K + (k0 + gc*8), &b_lds[c*8]);
    }
    __syncthreads();
    #pragma unroll
    for (int kc = 0; kc < 2; ++kc){
      bf16x8 af[4], bf_[4];
      #pragma unroll
      for (int mt = 0; mt < 4; ++mt){
        int row = wr*64 + mt*16 + lr;
        int off = row*128 + ((kc*64 + g*16) ^ ((row & 7) << 4));
        af[mt] = *(const bf16x8*)((const char*)a_lds + off);
      }
      #pragma unroll
      for (int nt = 0; nt < 4; ++nt){
        int row = wc*64 + nt*16 + lr;
        int off = row*128 + ((kc*64 + g*16) ^ ((row & 7) << 4));
        bf_[nt] = *(const bf16x8*)((const char*)b_lds + off);
      }
      #pragma unroll
      for (int mt = 0; mt < 4; ++mt)
        #pragma unroll
        for (int nt = 0; nt < 4; ++nt)
          acc[mt][nt] = __builtin_amdgcn_mfma_f32_16x16x32_bf16(af[mt], bf_[nt], acc[mt][nt], 0, 0, 0);
    }
  }
  #pragma unroll
  for (int mt = 0; mt < 4; ++mt){
    #pragma unroll
    for (int nt = 0; nt < 4; ++nt){
      const int col = n0 + wc*64 + nt*16 + lr;
      #pragma unroll
      for (int r = 0; r < 4; ++r){
        const int row = m0 + wr*64 + mt*16 + 4*g + r;   // C/D: col=lane&15, row=(lane>>4)*4+r (m89)
        if (F32OUT) ((float*)Cp)[(size_t)row*N + col] = acc[mt][nt][r] * oscale;
        else ((unsigned short*)Cp)[(size_t)row*N + col] = f2bf(acc[mt][nt][r] * oscale);
      }
    }
  }
}

// ---- per-tile softmax over 8 kc sub-tiles (exp2 domain; T13 defer-max THR=8) ----
static __device__ __forceinline__ void softmax_tile8(
    f32x4 (&s)[8], float& m_run, float& l_run, f32x4 (&acc)[4],
    bf16x4 (&pb)[8], int j0, int qg, int g, bool fullTile)
{
  float p[8][4];
  float tm = NEG_INF;
  if (fullTile){
    #pragma unroll
    for (int kc = 0; kc < 8; ++kc)
      #pragma unroll
      for (int r = 0; r < 4; ++r){
        p[kc][r] = s[kc][r];
        tm = fmaxf(tm, s[kc][r]);
      }
  } else {
    #pragma unroll
    for (int kc = 0; kc < 8; ++kc)
      #pragma unroll
      for (int r = 0; r < 4; ++r){
        int kvg = j0 + kc*16 + 4*g + r;
        float v = (kvg <= qg) ? s[kc][r] : NEG_INF;
        p[kc][r] = v;
        tm = fmaxf(tm, v);
      }
  }
  tm = fmaxf(tm, __shfl_xor(tm, 16));
  tm = fmaxf(tm, __shfl_xor(tm, 32));
  float ps = 0.f;
  if (__all(tm - m_run <= 8.f)){                       // defer: P bounded by 2^8
    const float mm = m_run;
    #pragma unroll
    for (int kc = 0; kc < 8; ++kc)
      #pragma unroll
      for (int r = 0; r < 4; ++r){
        float e = EXP2(p[kc][r] - mm);
        p[kc][r] = e; ps += e;
      }
    ps += __shfl_xor(ps, 16);
    ps += __shfl_xor(ps, 32);
    l_run += ps;
  } else {
    const float m_new = fmaxf(m_run, tm);
    const float fac = EXP2(m_run - m_new);             // first tile: exp2(-inf)=0
    #pragma unroll
    for (int kc = 0; kc < 8; ++kc)
      #pragma unroll
      for (int r = 0; r < 4; ++r){
        float e = EXP2(p[kc][r] - m_new);
        p[kc][r] = e; ps += e;
      }
    ps += __shfl_xor(ps, 16);
    ps += __shfl_xor(ps, 32);
    l_run = l_run * fac + ps;
    m_run = m_new;
    #pragma unroll
    for (int mt = 0; mt < 4; ++mt){
      acc[mt][0] *= fac; acc[mt][1] *= fac; acc[mt][2] *= fac; acc[mt][3] *= fac;
    }
  }
  #pragma unroll
  for (int kc = 0; kc < 8; ++kc){
    bf16x4 t;
    t[0] = (short)f2bfc(p[kc][0]); t[1] = (short)f2bfc(p[kc][1]);
    t[2] = (short)f2bfc(p[kc][2]); t[3] = (short)f2bfc(p[kc][3]);
    pb[kc] = t;
  }
}

// ---------------- causal flash attention ----------------
// Grid: 512 linear; decode L -> xcd=L&7, idx=L>>3, bh=xcd*8+(idx&7), pair=idx>>3.
// Each block processes TWO q-blocks sequentially: qblk=15-pair (heavy) then
// qblk=pair (light) -> every block = exactly 17 staging rounds: perfect static
// balance, uniform finish. XCD grouping keeps K/V L2-resident.
// Block: 8 waves x 512 thr; QBLK=128 (wave w owns q-rows q0+w*16..+15, one
// chain), KVBLK=128 (halved rounds vs 64), double-buffered prefetch, one
// barrier per round. With 128-wide kv tiles no wave is ever fully masked ->
// zero causal wave-skew; only the final diagonal tile masks per-element.
// Swapped QK^T (S^T = mfma(K,Q)); Q pre-scaled by log2e/sqrt(dk) (exp2 domain).
// PV: O^T = V^T @ P^T via mfma_16x16x16bf16_1k; Vt[n][t] pre-transposed by GEMM.
// LDS: K tile [128kv][64dk] swz (row&7); V tile [64dk][128kv] swz (row&15).
__global__ __launch_bounds__(512, 4) void attn_kernel(const unsigned short* __restrict__ Qg,
                                                      const unsigned short* __restrict__ Kg,
                                                      const unsigned short* __restrict__ Vt,
                                                      unsigned short* __restrict__ Og)
{
  __shared__ __attribute__((aligned(16))) unsigned short k_lds[2][128*64];
  __shared__ __attribute__((aligned(16))) unsigned short v_lds[2][64*128];
  const int tid = threadIdx.x;
  const int w = tid >> 6, l = tid & 63;
  const int g = l >> 4, lr = l & 15;
  const int L = blockIdx.x;
  const int xcd = L & 7, idx = L >> 3;
  const int bh = xcd*8 + (idx & 7);
  const int pair = idx >> 3;                            // 0..7
  const int b = bh >> 4, h = bh & 15;
  const size_t baseK = (size_t)(b*T_SEQ)*DM + h*DKH;            // K rows [t][n]
  const size_t baseV = (size_t)(h*DKH)*MROWS + (size_t)b*T_SEQ; // Vt rows [n][t]

  // staging geometry: 2048 chunks of 16B per round (K 1024 + V 1024), 4/thread
  const int cA = tid, cB = tid + 512;
  const int krA = cA >> 3, kgA = (cA & 7) ^ (krA & 7);
  const int krB = cB >> 3, kgB = (cB & 7) ^ (krB & 7);
  const int vrA = cA >> 4, vgA = (cA & 15) ^ (vrA & 15);
  const int vrB = cB >> 4, vgB = (cB & 15) ^ (vrB & 15);

  auto STAGE = [&](int jt, int buf){
    const int j0s = jt * 128;
    gload_lds16(Kg + baseK + (size_t)(j0s + krA)*DM + kgA*8, &k_lds[buf][cA*8]);
    gload_lds16(Kg + baseK + (size_t)(j0s + krB)*DM + kgB*8, &k_lds[buf][cB*8]);
    gload_lds16(Vt + baseV + (size_t)vrA*MROWS + j0s + vgA*8, &v_lds[buf][cA*8]);
    gload_lds16(Vt + baseV + (size_t)vrB*MROWS + j0s + vgB*8, &v_lds[buf][cB*8]);
  };

  #pragma unroll 1
  for (int seg = 0; seg < 2; ++seg){
    const int qblk = seg ? pair : (15 - pair);
    const int q0 = qblk * 128;
    const int qlo = q0 + w*16;
    const int qg = qlo + lr;                            // this lane's q row
    const size_t rowQ = (size_t)(b*T_SEQ + qg)*DM + h*DKH;
    bf16x8 qf[2];
    qf[0] = *(const bf16x8*)(Qg + rowQ + g*8);
    qf[1] = *(const bf16x8*)(Qg + rowQ + 32 + g*8);
    float m_run = NEG_INF, l_run = 0.f;
    f32x4 acc[4] = {};                                  // acc[mt]: O^T[dk=16mt+4g+r][q=lr]
    const int ntiles = qblk + 1;

    STAGE(0, 0);
    __syncthreads();                                    // drains vmcnt -> buf0 ready

    for (int jt = 0; jt < ntiles; ++jt){
      const int cur = jt & 1;
      if (jt + 1 < ntiles) STAGE(jt + 1, cur ^ 1);      // prefetch (hidden under compute)
      const int j0 = jt * 128;

      // QK^T (swapped): S^T sub-tiles, kv=16 each, kc 0..7
      f32x4 s[8];
      __builtin_amdgcn_s_setprio(1);
      #pragma unroll
      for (int kc = 0; kc < 8; ++kc){
        f32x4 z = {};
        #pragma unroll
        for (int c2 = 0; c2 < 2; ++c2){
          int row = kc*16 + lr;
          int off = row*128 + ((c2*64 + g*16) ^ ((row & 7) << 4));
          bf16x8 kf = *(const bf16x8*)((const char*)k_lds[cur] + off);
          z = __builtin_amdgcn_mfma_f32_16x16x32_bf16(kf, qf[c2], z, 0, 0, 0);
        }
        s[kc] = z;
      }
      __builtin_amdgcn_s_setprio(0);
      bf16x4 pb[8];
      softmax_tile8(s, m_run, l_run, acc, pb, j0, qg, g, jt < qblk);
      // PV: A-frag = V^T[dk=mt*16+lr][kv=kc*16+4g..+3], swizzled 8B read from v_lds
      __builtin_amdgcn_s_setprio(1);
      #pragma unroll
      for (int mt = 0; mt < 4; ++mt){
        const int vrow = mt*16 + lr;
        #pragma unroll
        for (int kc = 0; kc < 8; ++kc){
          const int voff = vrow*256 + ((((kc<<1) + (g>>1)) ^ (vrow & 15)) << 4) + ((g & 1) << 3);
          bf16x4 vf = *(const bf16x4*)((const char*)v_lds[cur] + voff);
          acc[mt] = __builtin_amdgcn_mfma_f32_16x16x16bf16_1k(vf, pb[kc], acc[mt], 0, 0, 0);
        }
      }
      __builtin_amdgcn_s_setprio(0);
      __syncthreads();                                  // buf[cur] free; prefetch drained
    }
    // epilogue: normalize, pack pairs (cvt_pk), store bf16
    const float inv = 1.f / l_run;
    const size_t rowO = (size_t)(b*T_SEQ + qg)*DM + h*DKH;
    #pragma unroll
    for (int mt = 0; mt < 4; ++mt){
      unsigned u0 = (unsigned)f2bfc(acc[mt][0]*inv) | ((unsigned)f2bfc(acc[mt][1]*inv) << 16);
      unsigned u1 = (unsigned)f2bfc(acc[mt][2]*inv) | ((unsigned)f2bfc(acc[mt][3]*inv) << 16);
      *(unsigned*)(Og + rowO + mt*16 + 4*g)     = u0;
      *(unsigned*)(Og + rowO + mt*16 + 4*g + 2) = u1;
    }
    // seg boundary: loop's final __syncthreads ordered all LDS reads before
    // next segment's STAGE overwrites buf0.
  }
}

// ---------------- launch ----------------
extern "C" void kernel_launch(void* const* d_in, const int* in_sizes, int n_in,
                              void* d_out, int out_size, void* d_ws, size_t ws_size,
                              hipStream_t stream)
{
  (void)in_sizes; (void)n_in; (void)out_size; (void)ws_size;
  const float* H  = (const float*)d_in[0];
  const float* Wq = (const float*)d_in[1];
  const float* Wk = (const float*)d_in[2];
  const float* Wv = (const float*)d_in[3];
  const float* Wo = (const float*)d_in[4];
  char* ws = (char*)d_ws;
  // ws layout (bytes): Hb 16MB | Wq/Wk/Wv/Wo^T bf16 2MB each | Q,K 16MB each | Vt 16MB | Ab 16MB = 88MB
  unsigned short* Hb  = (unsigned short*)(ws);
  unsigned short* Wqt = (unsigned short*)(ws + 16777216);
  unsigned short* Wkt = (unsigned short*)(ws + 18874368);
  unsigned short* Wvt = (unsigned short*)(ws + 20971520);
  unsigned short* Wot = (unsigned short*)(ws + 23068672);
  unsigned short* Qb  = (unsigned short*)(ws + 25165824);
  unsigned short* Kb  = (unsigned short*)(ws + 41943040);
  unsigned short* Vtb = (unsigned short*)(ws + 58720256);
  unsigned short* Ab  = (unsigned short*)(ws + 75497472);

  convh<<<2048, 256, 0, stream>>>((const float4*)H, (u16x4*)Hb, MROWS*DM/4);
  convw<<<dim3(32,32,4), dim3(32,8), 0, stream>>>(Wq, Wk, Wv, Wo, Wqt, Wkt, Wvt, Wot);
  // Q pre-scaled by log2e/sqrt(64) for exp2-domain softmax
  gemm_bt<false><<<dim3(64,8), 256, 0, stream>>>(Hb, Wqt, Qb, MROWS, DM, DM, 0.18033688f);
  gemm_bt<false><<<dim3(64,8), 256, 0, stream>>>(Hb, Wkt, Kb, MROWS, DM, DM, 1.0f);
  // V^T = (H Wv)^T computed directly: C[n][t] = sum_k Wvt[n][k] * Hb[t][k]
  gemm_bt<false><<<dim3(8,64), 256, 0, stream>>>(Wvt, Hb, Vtb, DM, MROWS, DM, 1.0f);
  attn_kernel<<<dim3(512), 512, 0, stream>>>(Qb, Kb, Vtb, Ab);
  gemm_bt<true><<<dim3(64,8), 256, 0, stream>>>(Ab, Wot, d_out, MROWS, DM, DM, 1.0f);
}

// Round 8
// 181.666 us; speedup vs baseline: 1.2479x; 1.0622x over previous
//
#include <hip/hip_runtime.h>
#include <hip/hip_bf16.h>

#define T_SEQ 2048
#define DM 1024
#define DM2 2048
#define NH 16
#define DKH 64
#define NBATCH 4
#define MROWS (NBATCH*T_SEQ)   // 8192

typedef __attribute__((ext_vector_type(8))) short bf16x8;
typedef __attribute__((ext_vector_type(4))) short bf16x4;
typedef __attribute__((ext_vector_type(4))) float f32x4;
typedef __attribute__((ext_vector_type(4))) unsigned short u16x4;

#define NEG_INF (-__builtin_inff())

#if __has_builtin(__builtin_amdgcn_exp2f)
#define EXP2(x) __builtin_amdgcn_exp2f(x)
#else
#define EXP2(x) exp2f(x)
#endif

static __device__ __forceinline__ unsigned short f2bf(float f){
  union { float f; unsigned u; } v; v.f = f;
  unsigned r = v.u + 0x7fffu + ((v.u >> 16) & 1u);
  return (unsigned short)(r >> 16);
}

// RTNE float->bf16 via HW cvt (compiler fuses pairs into v_cvt_pk_bf16_f32, m240)
static __device__ __forceinline__ unsigned short f2bfc(float f){
  union { __hip_bfloat16 h; unsigned short u; } cv;
  cv.h = __float2bfloat16(f);
  return cv.u;
}

static __device__ __forceinline__ void gload_lds16(const void* g, void* l){
  __builtin_amdgcn_global_load_lds(
      (const __attribute__((address_space(1))) void*)g,
      (__attribute__((address_space(3))) void*)l, 16, 0, 0);
}

// ---------------- convert H (fp32 -> bf16) ----------------
__global__ void convh(const float4* __restrict__ in, u16x4* __restrict__ out, int n4){
  for (int i = blockIdx.x*blockDim.x + threadIdx.x; i < n4; i += gridDim.x*blockDim.x){
    float4 v = in[i];
    u16x4 o;
    o[0] = f2bf(v.x); o[1] = f2bf(v.y); o[2] = f2bf(v.z); o[3] = f2bf(v.w);
    out[i] = o;
  }
}

// ------------- convert + transpose weights (fp32 [k][n] -> bf16 [n][k]) -------------
// Wq (z==0) is pre-scaled by log2e/sqrt(dk): folds the softmax scale into the
// Q projection exactly (GEMM is linear), enabling the fused Q|K GEMM.
__global__ void convw(const float* __restrict__ W0, const float* __restrict__ W1,
                      const float* __restrict__ W2, const float* __restrict__ W3,
                      unsigned short* __restrict__ O0, unsigned short* __restrict__ O1,
                      unsigned short* __restrict__ O2, unsigned short* __restrict__ O3)
{
  const float* W = (blockIdx.z==0)?W0:(blockIdx.z==1)?W1:(blockIdx.z==2)?W2:W3;
  unsigned short* O = (blockIdx.z==0)?O0:(blockIdx.z==1)?O1:(blockIdx.z==2)?O2:O3;
  const float sc = (blockIdx.z==0) ? 0.18033688f : 1.0f;   // log2e/8
  __shared__ float t[32][33];
  const int nx = blockIdx.x*32, kx = blockIdx.y*32;
  const int tx = threadIdx.x, ty = threadIdx.y;
  #pragma unroll
  for (int i = 0; i < 4; ++i)
    t[ty + i*8][tx] = W[(size_t)(kx + ty + i*8)*DM + nx + tx];
  __syncthreads();
  #pragma unroll
  for (int i = 0; i < 4; ++i)
    O[(size_t)(nx + ty + i*8)*DM + kx + tx] = f2bf(t[tx][ty + i*8] * sc);
}

// ---------------- GEMM: C[M][N] = A[M][K](bf16) * Bt[N][K](bf16)^T ----------------
// 128x128 tile, BK=64, 4 waves (2x2), 16x16x32 bf16 MFMA, global_load_lds staging,
// XOR-swizzled LDS ((row&7) chunk-XOR within 128B rows) for conflict-free ds_read_b128.
template<bool F32OUT>
__global__ __launch_bounds__(256) void gemm_bt(const unsigned short* __restrict__ A,
                                               const unsigned short* __restrict__ Bt,
                                               void* __restrict__ Cp,
                                               int M, int N, int K)
{
  __shared__ __attribute__((aligned(16))) unsigned short a_lds[128*64];
  __shared__ __attribute__((aligned(16))) unsigned short b_lds[128*64];
  const int tid = threadIdx.x;
  const int w = tid >> 6, l = tid & 63;
  const int g = l >> 4, lr = l & 15;
  const int wr = w >> 1, wc = w & 1;
  const int m0 = blockIdx.x * 128, n0 = blockIdx.y * 128;
  f32x4 acc[4][4] = {};
  const int nk = K >> 6;
  for (int ks = 0; ks < nk; ++ks){
    __syncthreads();
    const int k0 = ks << 6;
    #pragma unroll
    for (int i = 0; i < 4; ++i){
      int c = (w*4 + i)*64 + l;           // 0..1023, 16B chunks
      int row = c >> 3;
      int gc = (c & 7) ^ (row & 7);       // pre-swizzled global source (m173 pattern)
      gload_lds16(A + (size_t)(m0 + row)*K + (k0 + gc*8), &a_lds[c*8]);
    }
    #pragma unroll
    for (int i = 0; i < 4; ++i){
      int c = (w*4 + i)*64 + l;
      int row = c >> 3;
      int gc = (c & 7) ^ (row & 7);
      gload_lds16(Bt + (size_t)(n0 + row)*K + (k0 + gc*8), &b_lds[c*8]);
    }
    __syncthreads();
    #pragma unroll
    for (int kc = 0; kc < 2; ++kc){
      bf16x8 af[4], bf_[4];
      #pragma unroll
      for (int mt = 0; mt < 4; ++mt){
        int row = wr*64 + mt*16 + lr;
        int off = row*128 + ((kc*64 + g*16) ^ ((row & 7) << 4));
        af[mt] = *(const bf16x8*)((const char*)a_lds + off);
      }
      #pragma unroll
      for (int nt = 0; nt < 4; ++nt){
        int row = wc*64 + nt*16 + lr;
        int off = row*128 + ((kc*64 + g*16) ^ ((row & 7) << 4));
        bf_[nt] = *(const bf16x8*)((const char*)b_lds + off);
      }
      #pragma unroll
      for (int mt = 0; mt < 4; ++mt)
        #pragma unroll
        for (int nt = 0; nt < 4; ++nt)
          acc[mt][nt] = __builtin_amdgcn_mfma_f32_16x16x32_bf16(af[mt], bf_[nt], acc[mt][nt], 0, 0, 0);
    }
  }
  #pragma unroll
  for (int mt = 0; mt < 4; ++mt){
    #pragma unroll
    for (int nt = 0; nt < 4; ++nt){
      const int col = n0 + wc*64 + nt*16 + lr;
      #pragma unroll
      for (int r = 0; r < 4; ++r){
        const int row = m0 + wr*64 + mt*16 + 4*g + r;   // C/D: col=lane&15, row=(lane>>4)*4+r (m89)
        if (F32OUT) ((float*)Cp)[(size_t)row*N + col] = acc[mt][nt][r];
        else ((unsigned short*)Cp)[(size_t)row*N + col] = f2bf(acc[mt][nt][r]);
      }
    }
  }
}

// ---- per-tile softmax over 8 kc sub-tiles (exp2 domain; T13 defer-max THR=8) ----
// In-place on s (no p[] copy); max3-fusable trees; 4-way partial denominator sums.
static __device__ __forceinline__ void softmax_tile8(
    f32x4 (&s)[8], float& m_run, float& l_run, f32x4 (&acc)[4],
    bf16x4 (&pb)[8], int j0, int qg, int g, bool fullTile)
{
  if (!fullTile){
    #pragma unroll
    for (int kc = 0; kc < 8; ++kc)
      #pragma unroll
      for (int r = 0; r < 4; ++r){
        int kvg = j0 + kc*16 + 4*g + r;
        s[kc][r] = (kvg <= qg) ? s[kc][r] : NEG_INF;
      }
  }
  // tile max: per-kc max4 then 8->1 (fmaxf nests fuse to v_max3)
  float m4[8];
  #pragma unroll
  for (int kc = 0; kc < 8; ++kc)
    m4[kc] = fmaxf(fmaxf(s[kc][0], s[kc][1]), fmaxf(s[kc][2], s[kc][3]));
  float tm = fmaxf(fmaxf(fmaxf(m4[0], m4[1]), fmaxf(m4[2], m4[3])),
                   fmaxf(fmaxf(m4[4], m4[5]), fmaxf(m4[6], m4[7])));
  tm = fmaxf(tm, __shfl_xor(tm, 16));
  tm = fmaxf(tm, __shfl_xor(tm, 32));
  float mm;
  if (__all(tm - m_run <= 8.f)){                       // defer: P bounded by 2^8
    mm = m_run;
  } else {
    const float m_new = fmaxf(m_run, tm);
    const float fac = EXP2(m_run - m_new);             // first tile: exp2(-inf)=0
    l_run *= fac;
    m_run = m_new; mm = m_new;
    #pragma unroll
    for (int mt = 0; mt < 4; ++mt){
      acc[mt][0] *= fac; acc[mt][1] *= fac; acc[mt][2] *= fac; acc[mt][3] *= fac;
    }
  }
  float ps0 = 0.f, ps1 = 0.f, ps2 = 0.f, ps3 = 0.f;    // 4 parallel 8-deep chains
  #pragma unroll
  for (int kc = 0; kc < 8; ++kc){
    float e0 = EXP2(s[kc][0] - mm); float e1 = EXP2(s[kc][1] - mm);
    float e2 = EXP2(s[kc][2] - mm); float e3 = EXP2(s[kc][3] - mm);
    s[kc][0] = e0; s[kc][1] = e1; s[kc][2] = e2; s[kc][3] = e3;
    ps0 += e0; ps1 += e1; ps2 += e2; ps3 += e3;
  }
  float ps = (ps0 + ps1) + (ps2 + ps3);
  ps += __shfl_xor(ps, 16);
  ps += __shfl_xor(ps, 32);
  l_run += ps;
  #pragma unroll
  for (int kc = 0; kc < 8; ++kc){
    bf16x4 t;
    t[0] = (short)f2bfc(s[kc][0]); t[1] = (short)f2bfc(s[kc][1]);
    t[2] = (short)f2bfc(s[kc][2]); t[3] = (short)f2bfc(s[kc][3]);
    pb[kc] = t;
  }
}

// ---------------- causal flash attention ----------------
// Grid: 512 linear; decode L -> xcd=L&7, idx=L>>3, bh=xcd*8+(idx&7), pair=idx>>3.
// Each block processes TWO q-blocks sequentially: qblk=15-pair then pair ->
// every block = exactly 17 staging rounds: perfect static balance. XCD grouping
// keeps K/V L2-resident. Block: 8 waves x 512 thr; QBLK=128, KVBLK=128,
// double-buffered prefetch, one barrier per round.
// Q/K come from the FUSED QK buffer [8192][2048] (Q cols 0-1023, K cols
// 1024-2047); Q pre-scaled by log2e/sqrt(dk) via Wq. Swapped QK^T
// (S^T = mfma(K,Q)). PV: O^T = V^T @ P^T via mfma_16x16x16bf16_1k;
// Vt[n][t] pre-transposed by GEMM.
// LDS: K tile [128kv][64dk] swz (row&7); V tile [64dk][128kv] swz (row&15).
__global__ __launch_bounds__(512, 4) void attn_kernel(const unsigned short* __restrict__ QK,
                                                      const unsigned short* __restrict__ Vt,
                                                      unsigned short* __restrict__ Og)
{
  __shared__ __attribute__((aligned(16))) unsigned short k_lds[2][128*64];
  __shared__ __attribute__((aligned(16))) unsigned short v_lds[2][64*128];
  const int tid = threadIdx.x;
  const int w = tid >> 6, l = tid & 63;
  const int g = l >> 4, lr = l & 15;
  const int L = blockIdx.x;
  const int xcd = L & 7, idx = L >> 3;
  const int bh = xcd*8 + (idx & 7);
  const int pair = idx >> 3;                            // 0..7
  const int b = bh >> 4, h = bh & 15;
  const size_t baseK = (size_t)(b*T_SEQ)*DM2 + 1024 + h*DKH;    // K rows in QK [t][2048]
  const size_t baseV = (size_t)(h*DKH)*MROWS + (size_t)b*T_SEQ; // Vt rows [n][t]

  // staging geometry: 2048 chunks of 16B per round (K 1024 + V 1024), 4/thread
  const int cA = tid, cB = tid + 512;
  const int krA = cA >> 3, kgA = (cA & 7) ^ (krA & 7);
  const int krB = cB >> 3, kgB = (cB & 7) ^ (krB & 7);
  const int vrA = cA >> 4, vgA = (cA & 15) ^ (vrA & 15);
  const int vrB = cB >> 4, vgB = (cB & 15) ^ (vrB & 15);

  auto STAGE = [&](int jt, int buf){
    const int j0s = jt * 128;
    gload_lds16(QK + baseK + (size_t)(j0s + krA)*DM2 + kgA*8, &k_lds[buf][cA*8]);
    gload_lds16(QK + baseK + (size_t)(j0s + krB)*DM2 + kgB*8, &k_lds[buf][cB*8]);
    gload_lds16(Vt + baseV + (size_t)vrA*MROWS + j0s + vgA*8, &v_lds[buf][cA*8]);
    gload_lds16(Vt + baseV + (size_t)vrB*MROWS + j0s + vgB*8, &v_lds[buf][cB*8]);
  };

  #pragma unroll 1
  for (int seg = 0; seg < 2; ++seg){
    const int qblk = seg ? pair : (15 - pair);
    const int q0 = qblk * 128;
    const int qlo = q0 + w*16;
    const int qg = qlo + lr;                            // this lane's q row
    const size_t rowQ = (size_t)(b*T_SEQ + qg)*DM2 + h*DKH;
    bf16x8 qf[2];
    qf[0] = *(const bf16x8*)(QK + rowQ + g*8);
    qf[1] = *(const bf16x8*)(QK + rowQ + 32 + g*8);
    float m_run = NEG_INF, l_run = 0.f;
    f32x4 acc[4] = {};                                  // acc[mt]: O^T[dk=16mt+4g+r][q=lr]
    const int ntiles = qblk + 1;

    STAGE(0, 0);
    __syncthreads();                                    // drains vmcnt -> buf0 ready

    for (int jt = 0; jt < ntiles; ++jt){
      const int cur = jt & 1;
      if (jt + 1 < ntiles) STAGE(jt + 1, cur ^ 1);      // prefetch (hidden under compute)
      const int j0 = jt * 128;

      // QK^T (swapped): S^T sub-tiles, kv=16 each, kc 0..7
      f32x4 s[8];
      __builtin_amdgcn_s_setprio(1);
      #pragma unroll
      for (int kc = 0; kc < 8; ++kc){
        f32x4 z = {};
        #pragma unroll
        for (int c2 = 0; c2 < 2; ++c2){
          int row = kc*16 + lr;
          int off = row*128 + ((c2*64 + g*16) ^ ((row & 7) << 4));
          bf16x8 kf = *(const bf16x8*)((const char*)k_lds[cur] + off);
          z = __builtin_amdgcn_mfma_f32_16x16x32_bf16(kf, qf[c2], z, 0, 0, 0);
        }
        s[kc] = z;
      }
      __builtin_amdgcn_s_setprio(0);
      bf16x4 pb[8];
      softmax_tile8(s, m_run, l_run, acc, pb, j0, qg, g, jt < qblk);
      // PV: A-frag = V^T[dk=mt*16+lr][kv=kc*16+4g..+3], swizzled 8B read from v_lds
      __builtin_amdgcn_s_setprio(1);
      #pragma unroll
      for (int mt = 0; mt < 4; ++mt){
        const int vrow = mt*16 + lr;
        #pragma unroll
        for (int kc = 0; kc < 8; ++kc){
          const int voff = vrow*256 + ((((kc<<1) + (g>>1)) ^ (vrow & 15)) << 4) + ((g & 1) << 3);
          bf16x4 vf = *(const bf16x4*)((const char*)v_lds[cur] + voff);
          acc[mt] = __builtin_amdgcn_mfma_f32_16x16x16bf16_1k(vf, pb[kc], acc[mt], 0, 0, 0);
        }
      }
      __builtin_amdgcn_s_setprio(0);
      __syncthreads();                                  // buf[cur] free; prefetch drained
    }
    // epilogue: normalize, pack pairs (cvt_pk), store bf16
    const float inv = 1.f / l_run;
    const size_t rowO = (size_t)(b*T_SEQ + qg)*DM + h*DKH;
    #pragma unroll
    for (int mt = 0; mt < 4; ++mt){
      unsigned u0 = (unsigned)f2bfc(acc[mt][0]*inv) | ((unsigned)f2bfc(acc[mt][1]*inv) << 16);
      unsigned u1 = (unsigned)f2bfc(acc[mt][2]*inv) | ((unsigned)f2bfc(acc[mt][3]*inv) << 16);
      *(unsigned*)(Og + rowO + mt*16 + 4*g)     = u0;
      *(unsigned*)(Og + rowO + mt*16 + 4*g + 2) = u1;
    }
    // seg boundary: loop's final __syncthreads ordered all LDS reads before
    // next segment's STAGE overwrites buf0.
  }
}

// ---------------- launch ----------------
extern "C" void kernel_launch(void* const* d_in, const int* in_sizes, int n_in,
                              void* d_out, int out_size, void* d_ws, size_t ws_size,
                              hipStream_t stream)
{
  (void)in_sizes; (void)n_in; (void)out_size; (void)ws_size;
  const float* H  = (const float*)d_in[0];
  const float* Wq = (const float*)d_in[1];
  const float* Wk = (const float*)d_in[2];
  const float* Wv = (const float*)d_in[3];
  const float* Wo = (const float*)d_in[4];
  char* ws = (char*)d_ws;
  // ws layout (bytes): Hb 16MB | Wq^T|Wk^T (contiguous 2048x1024) 4MB | Wv^T 2MB |
  // Wo^T 2MB | QK [8192][2048] 32MB | Vt 16MB | Ab 16MB = 88MB
  unsigned short* Hb   = (unsigned short*)(ws);
  unsigned short* Wqkt = (unsigned short*)(ws + 16777216);   // rows 0-1023: Wq^T (scaled), 1024-2047: Wk^T
  unsigned short* Wkt  = (unsigned short*)(ws + 18874368);
  unsigned short* Wvt  = (unsigned short*)(ws + 20971520);
  unsigned short* Wot  = (unsigned short*)(ws + 23068672);
  unsigned short* QKb  = (unsigned short*)(ws + 25165824);   // 32MB
  unsigned short* Vtb  = (unsigned short*)(ws + 58720256);
  unsigned short* Ab   = (unsigned short*)(ws + 75497472);

  convh<<<2048, 256, 0, stream>>>((const float4*)H, (u16x4*)Hb, MROWS*DM/4);
  convw<<<dim3(32,32,4), dim3(32,8), 0, stream>>>(Wq, Wk, Wv, Wo, Wqkt, Wkt, Wvt, Wot);
  // Fused Q|K projection: C[8192][2048] = Hb @ (Wq|Wk)^T
  gemm_bt<false><<<dim3(64,16), 256, 0, stream>>>(Hb, Wqkt, QKb, MROWS, DM2, DM);
  // V^T = (H Wv)^T computed directly: C[n][t] = sum_k Wvt[n][k] * Hb[t][k]
  gemm_bt<false><<<dim3(8,64), 256, 0, stream>>>(Wvt, Hb, Vtb, DM, MROWS, DM);
  attn_kernel<<<dim3(512), 512, 0, stream>>>(QKb, Vtb, Ab);
  gemm_bt<true><<<dim3(64,8), 256, 0, stream>>>(Ab, Wot, d_out, MROWS, DM, DM);
}

// Round 9
// 171.212 us; speedup vs baseline: 1.3241x; 1.0611x over previous
//
#include <hip/hip_runtime.h>
#include <hip/hip_bf16.h>

#define T_SEQ 2048
#define DM 1024
#define DM2 2048
#define NH 16
#define DKH 64
#define NBATCH 4
#define MROWS (NBATCH*T_SEQ)   // 8192

typedef __attribute__((ext_vector_type(8))) short bf16x8;
typedef __attribute__((ext_vector_type(4))) short bf16x4;
typedef __attribute__((ext_vector_type(4))) float f32x4;
typedef __attribute__((ext_vector_type(4))) unsigned short u16x4;

#define NEG_INF (-__builtin_inff())

#if __has_builtin(__builtin_amdgcn_exp2f)
#define EXP2(x) __builtin_amdgcn_exp2f(x)
#else
#define EXP2(x) exp2f(x)
#endif

static __device__ __forceinline__ unsigned short f2bf(float f){
  union { float f; unsigned u; } v; v.f = f;
  unsigned r = v.u + 0x7fffu + ((v.u >> 16) & 1u);
  return (unsigned short)(r >> 16);
}

// RTNE float->bf16 via HW cvt (compiler fuses pairs into v_cvt_pk_bf16_f32, m240)
static __device__ __forceinline__ unsigned short f2bfc(float f){
  union { __hip_bfloat16 h; unsigned short u; } cv;
  cv.h = __float2bfloat16(f);
  return cv.u;
}

static __device__ __forceinline__ void gload_lds16(const void* g, void* l){
  __builtin_amdgcn_global_load_lds(
      (const __attribute__((address_space(1))) void*)g,
      (__attribute__((address_space(3))) void*)l, 16, 0, 0);
}

// ---------- fused prep: H fp32->bf16 (grid tail) + weight convert/transpose ----------
// blocks 0..4095: convw (z = bid>>10); Wq pre-scaled by log2e/sqrt(dk).
// blocks 4096..6143: convh grid-stride.
__global__ __launch_bounds__(256) void convprep(
    const float* __restrict__ H,
    const float* __restrict__ W0, const float* __restrict__ W1,
    const float* __restrict__ W2, const float* __restrict__ W3,
    u16x4* __restrict__ Hb4,
    unsigned short* __restrict__ O0, unsigned short* __restrict__ O1,
    unsigned short* __restrict__ O2, unsigned short* __restrict__ O3)
{
  __shared__ float t[32][33];
  const int bid = blockIdx.x, tid = threadIdx.x;
  if (bid < 4096){
    const int z = bid >> 10, rem = bid & 1023;
    const int nx = (rem & 31)*32, kx = (rem >> 5)*32;
    const float* W = (z==0)?W0:(z==1)?W1:(z==2)?W2:W3;
    unsigned short* O = (z==0)?O0:(z==1)?O1:(z==2)?O2:O3;
    const float sc = (z==0) ? 0.18033688f : 1.0f;   // log2e/8 folded into Wq
    const int tx = tid & 31, ty = tid >> 5;
    #pragma unroll
    for (int i = 0; i < 4; ++i)
      t[ty + i*8][tx] = W[(size_t)(kx + ty + i*8)*DM + nx + tx];
    __syncthreads();
    #pragma unroll
    for (int i = 0; i < 4; ++i)
      O[(size_t)(nx + ty + i*8)*DM + kx + tx] = f2bf(t[tx][ty + i*8] * sc);
  } else {
    const int n4 = MROWS*DM/4;
    for (int i = (bid - 4096)*256 + tid; i < n4; i += 2048*256){
      float4 v = ((const float4*)H)[i];
      u16x4 o;
      o[0] = f2bf(v.x); o[1] = f2bf(v.y); o[2] = f2bf(v.z); o[3] = f2bf(v.w);
      Hb4[i] = o;
    }
  }
}

// ---------------- GEMM core (shared by both GEMM kernels) ----------------
// 128x128 tile, BK=64, 4 waves (2x2), 16x16x32 bf16 MFMA, global_load_lds staging,
// XOR-swizzled LDS ((row&7) chunk-XOR within 128B rows): conflict-free both sides.
template<bool F32OUT>
static __device__ __forceinline__ void gemm_body(
    const unsigned short* __restrict__ A, const unsigned short* __restrict__ Bt,
    void* __restrict__ Cp, int N, int K, int m0, int n0,
    unsigned short* a_lds, unsigned short* b_lds)
{
  const int tid = threadIdx.x;
  const int w = tid >> 6, l = tid & 63;
  const int g = l >> 4, lr = l & 15;
  const int wr = w >> 1, wc = w & 1;
  f32x4 acc[4][4] = {};
  const int nk = K >> 6;
  for (int ks = 0; ks < nk; ++ks){
    __syncthreads();
    const int k0 = ks << 6;
    #pragma unroll
    for (int i = 0; i < 4; ++i){
      int c = (w*4 + i)*64 + l;           // 0..1023, 16B chunks
      int row = c >> 3;
      int gc = (c & 7) ^ (row & 7);       // pre-swizzled global source (m173 pattern)
      gload_lds16(A + (size_t)(m0 + row)*K + (k0 + gc*8), &a_lds[c*8]);
    }
    #pragma unroll
    for (int i = 0; i < 4; ++i){
      int c = (w*4 + i)*64 + l;
      int row = c >> 3;
      int gc = (c & 7) ^ (row & 7);
      gload_lds16(Bt + (size_t)(n0 + row)*K + (k0 + gc*8), &b_lds[c*8]);
    }
    __syncthreads();
    #pragma unroll
    for (int kc = 0; kc < 2; ++kc){
      bf16x8 af[4], bf_[4];
      #pragma unroll
      for (int mt = 0; mt < 4; ++mt){
        int row = wr*64 + mt*16 + lr;
        int off = row*128 + ((kc*64 + g*16) ^ ((row & 7) << 4));
        af[mt] = *(const bf16x8*)((const char*)a_lds + off);
      }
      #pragma unroll
      for (int nt = 0; nt < 4; ++nt){
        int row = wc*64 + nt*16 + lr;
        int off = row*128 + ((kc*64 + g*16) ^ ((row & 7) << 4));
        bf_[nt] = *(const bf16x8*)((const char*)b_lds + off);
      }
      #pragma unroll
      for (int mt = 0; mt < 4; ++mt)
        #pragma unroll
        for (int nt = 0; nt < 4; ++nt)
          acc[mt][nt] = __builtin_amdgcn_mfma_f32_16x16x32_bf16(af[mt], bf_[nt], acc[mt][nt], 0, 0, 0);
    }
  }
  #pragma unroll
  for (int mt = 0; mt < 4; ++mt){
    #pragma unroll
    for (int nt = 0; nt < 4; ++nt){
      const int col = n0 + wc*64 + nt*16 + lr;
      #pragma unroll
      for (int r = 0; r < 4; ++r){
        const int row = m0 + wr*64 + mt*16 + 4*g + r;   // C/D: col=lane&15, row=(lane>>4)*4+r (m89)
        if (F32OUT) ((float*)Cp)[(size_t)row*N + col] = acc[mt][nt][r];
        else ((unsigned short*)Cp)[(size_t)row*N + col] = f2bf(acc[mt][nt][r]);
      }
    }
  }
}

// Fused QK-projection + V^T-projection dispatch: blocks 0..1023 compute
// QK[8192][2048] = Hb @ (Wq|Wk)^T; blocks 1024..1535 compute Vt[1024][8192]
// = Wvt @ Hb^T. One launch -> one less gap + tail overlap.
__global__ __launch_bounds__(256) void gemm_qkv(
    const unsigned short* __restrict__ Hb, const unsigned short* __restrict__ Wqkt,
    unsigned short* __restrict__ QKb,
    const unsigned short* __restrict__ Wvt, unsigned short* __restrict__ Vtb)
{
  __shared__ __attribute__((aligned(16))) unsigned short a_lds[128*64];
  __shared__ __attribute__((aligned(16))) unsigned short b_lds[128*64];
  const int bid = blockIdx.x;
  const unsigned short *A, *Bt; unsigned short* Cp; int N, m0, n0;
  if (bid < 1024){
    A = Hb; Bt = Wqkt; Cp = QKb; N = DM2;
    m0 = (bid & 63)*128; n0 = (bid >> 6)*128;
  } else {
    const int t2 = bid - 1024;
    A = Wvt; Bt = Hb; Cp = Vtb; N = MROWS;
    m0 = (t2 & 7)*128; n0 = (t2 >> 3)*128;
  }
  gemm_body<false>(A, Bt, Cp, N, DM, m0, n0, a_lds, b_lds);
}

// Output GEMM: d_out[8192][1024] fp32 = Ab @ Wo^T
__global__ __launch_bounds__(256) void gemm_out(
    const unsigned short* __restrict__ Ab, const unsigned short* __restrict__ Wot,
    float* __restrict__ Out)
{
  __shared__ __attribute__((aligned(16))) unsigned short a_lds[128*64];
  __shared__ __attribute__((aligned(16))) unsigned short b_lds[128*64];
  gemm_body<true>(Ab, Wot, Out, DM, DM, blockIdx.x*128, blockIdx.y*128, a_lds, b_lds);
}

// ---- per-tile softmax over 8 kc sub-tiles (exp2 domain; T13 defer-max THR=8) ----
// Denominator is NOT summed here: PV's ones-row MFMA accumulates it in acc[4].
static __device__ __forceinline__ void softmax_tile8(
    f32x4 (&s)[8], float& m_run, f32x4 (&acc)[5],
    bf16x4 (&pb)[8], int j0, int qg, int g, bool fullTile)
{
  if (!fullTile){
    #pragma unroll
    for (int kc = 0; kc < 8; ++kc)
      #pragma unroll
      for (int r = 0; r < 4; ++r){
        int kvg = j0 + kc*16 + 4*g + r;
        s[kc][r] = (kvg <= qg) ? s[kc][r] : NEG_INF;
      }
  }
  // tile max: per-kc max4 then 8->1 (fmaxf nests fuse to v_max3)
  float m4[8];
  #pragma unroll
  for (int kc = 0; kc < 8; ++kc)
    m4[kc] = fmaxf(fmaxf(s[kc][0], s[kc][1]), fmaxf(s[kc][2], s[kc][3]));
  float tm = fmaxf(fmaxf(fmaxf(m4[0], m4[1]), fmaxf(m4[2], m4[3])),
                   fmaxf(fmaxf(m4[4], m4[5]), fmaxf(m4[6], m4[7])));
  tm = fmaxf(tm, __shfl_xor(tm, 16));
  tm = fmaxf(tm, __shfl_xor(tm, 32));
  float mm;
  if (__all(tm - m_run <= 8.f)){                       // defer: P bounded by 2^8
    mm = m_run;
  } else {
    const float m_new = fmaxf(m_run, tm);
    const float fac = EXP2(m_run - m_new);             // first tile: exp2(-inf)=0
    m_run = m_new; mm = m_new;
    #pragma unroll
    for (int mt = 0; mt < 5; ++mt){                    // acc[4] = denominator tile
      acc[mt][0] *= fac; acc[mt][1] *= fac; acc[mt][2] *= fac; acc[mt][3] *= fac;
    }
  }
  #pragma unroll
  for (int kc = 0; kc < 8; ++kc){
    float e0 = EXP2(s[kc][0] - mm); float e1 = EXP2(s[kc][1] - mm);
    float e2 = EXP2(s[kc][2] - mm); float e3 = EXP2(s[kc][3] - mm);
    bf16x4 t;
    t[0] = (short)f2bfc(e0); t[1] = (short)f2bfc(e1);
    t[2] = (short)f2bfc(e2); t[3] = (short)f2bfc(e3);
    pb[kc] = t;
  }
}

// ---------------- causal flash attention ----------------
// Grid: 512 linear; decode L -> xcd=L&7, idx=L>>3, bh=xcd*8+(idx&7), pair=idx>>3.
// Each block: TWO q-blocks (15-pair, then pair) = exactly 17 staging rounds:
// perfect static balance; XCD grouping keeps K/V L2-resident.
// Block: 8 waves x 512 thr; QBLK=128, KVBLK=128, double-buffered prefetch, one
// barrier per round. Rounds processed in PAIRS with compile-time buffer parity
// (ROUND macro): all 48 LDS read addresses are loop-invariant.
// Swapped QK^T (S^T = mfma(K,Q)); Q pre-scaled by log2e/sqrt(dk) via Wq.
// PV: O^T = V^T @ P^T via mfma_16x16x16bf16_1k; acc[4] (A=ones) accumulates
// the softmax denominator on the matrix pipe (no VALU sums/shuffles).
// LDS: K tile [128kv][64dk] swz (row&7); V tile [64dk][128kv] swz (row&15).
__global__ __launch_bounds__(512, 4) void attn_kernel(const unsigned short* __restrict__ QK,
                                                      const unsigned short* __restrict__ Vt,
                                                      unsigned short* __restrict__ Og)
{
  __shared__ __attribute__((aligned(16))) unsigned short k_lds[2][128*64];
  __shared__ __attribute__((aligned(16))) unsigned short v_lds[2][64*128];
  const int tid = threadIdx.x;
  const int w = tid >> 6, l = tid & 63;
  const int g = l >> 4, lr = l & 15;
  const int L = blockIdx.x;
  const int xcd = L & 7, idx = L >> 3;
  const int bh = xcd*8 + (idx & 7);
  const int pair = idx >> 3;                            // 0..7
  const int b = bh >> 4, h = bh & 15;
  const size_t baseK = (size_t)(b*T_SEQ)*DM2 + 1024 + h*DKH;    // K rows in QK [t][2048]
  const size_t baseV = (size_t)(h*DKH)*MROWS + (size_t)b*T_SEQ; // Vt rows [n][t]
  const bf16x4 vone = {(short)0x3F80, (short)0x3F80, (short)0x3F80, (short)0x3F80};

  // staging geometry: 2048 chunks of 16B per round (K 1024 + V 1024), 4/thread
  const int cA = tid, cB = tid + 512;
  const int krA = cA >> 3, kgA = (cA & 7) ^ (krA & 7);
  const int krB = cB >> 3, kgB = (cB & 7) ^ (krB & 7);
  const int vrA = cA >> 4, vgA = (cA & 15) ^ (vrA & 15);
  const int vrB = cB >> 4, vgB = (cB & 15) ^ (vrB & 15);

  auto STAGE = [&](int jt, int buf){
    const int j0s = jt * 128;
    gload_lds16(QK + baseK + (size_t)(j0s + krA)*DM2 + kgA*8, &k_lds[buf][cA*8]);
    gload_lds16(QK + baseK + (size_t)(j0s + krB)*DM2 + kgB*8, &k_lds[buf][cB*8]);
    gload_lds16(Vt + baseV + (size_t)vrA*MROWS + j0s + vgA*8, &v_lds[buf][cA*8]);
    gload_lds16(Vt + baseV + (size_t)vrB*MROWS + j0s + vgB*8, &v_lds[buf][cB*8]);
  };

#define ROUND(JT, CUR) do{                                                       \
    const int jt_ = (JT);                                                        \
    if (jt_ + 1 < ntiles) STAGE(jt_ + 1, (CUR)^1);                               \
    const int j0_ = jt_ * 128;                                                   \
    f32x4 s[8];                                                                  \
    __builtin_amdgcn_s_setprio(1);                                               \
    _Pragma("unroll")                                                            \
    for (int kc = 0; kc < 8; ++kc){                                              \
      f32x4 z = {};                                                              \
      _Pragma("unroll")                                                          \
      for (int c2 = 0; c2 < 2; ++c2){                                            \
        int row = kc*16 + lr;                                                    \
        int off = row*128 + ((c2*64 + g*16) ^ ((row & 7) << 4));                 \
        bf16x8 kf = *(const bf16x8*)((const char*)k_lds[CUR] + off);             \
        z = __builtin_amdgcn_mfma_f32_16x16x32_bf16(kf, qf[c2], z, 0, 0, 0);     \
      }                                                                          \
      s[kc] = z;                                                                 \
    }                                                                            \
    __builtin_amdgcn_s_setprio(0);                                               \
    bf16x4 pb[8];                                                                \
    softmax_tile8(s, m_run, acc, pb, j0_, qg, g, jt_ < qblk);                    \
    __builtin_amdgcn_s_setprio(1);                                               \
    _Pragma("unroll")                                                            \
    for (int mt = 0; mt < 4; ++mt){                                              \
      const int vrow = mt*16 + lr;                                               \
      _Pragma("unroll")                                                          \
      for (int kc = 0; kc < 8; ++kc){                                            \
        const int voff = vrow*256 + ((((kc<<1) + (g>>1)) ^ (vrow & 15)) << 4)    \
                         + ((g & 1) << 3);                                       \
        bf16x4 vf = *(const bf16x4*)((const char*)v_lds[CUR] + voff);            \
        acc[mt] = __builtin_amdgcn_mfma_f32_16x16x16bf16_1k(vf, pb[kc], acc[mt], 0, 0, 0); \
      }                                                                          \
    }                                                                            \
    _Pragma("unroll")                                                            \
    for (int kc = 0; kc < 8; ++kc)                                               \
      acc[4] = __builtin_amdgcn_mfma_f32_16x16x16bf16_1k(vone, pb[kc], acc[4], 0, 0, 0); \
    __builtin_amdgcn_s_setprio(0);                                               \
    __syncthreads();                                                             \
  } while(0)

  #pragma unroll 1
  for (int seg = 0; seg < 2; ++seg){
    const int qblk = seg ? pair : (15 - pair);
    const int q0 = qblk * 128;
    const int qg = q0 + w*16 + lr;                      // this lane's q row
    const size_t rowQ = (size_t)(b*T_SEQ + qg)*DM2 + h*DKH;
    bf16x8 qf[2];
    qf[0] = *(const bf16x8*)(QK + rowQ + g*8);
    qf[1] = *(const bf16x8*)(QK + rowQ + 32 + g*8);
    float m_run = NEG_INF;
    f32x4 acc[5] = {};                                  // [0..3]: O^T tiles; [4]: denominator
    const int ntiles = qblk + 1;

    STAGE(0, 0);
    __syncthreads();                                    // drains vmcnt -> buf0 ready

    int jt = 0;
    #pragma unroll 1
    for (; jt + 2 <= ntiles; jt += 2){
      ROUND(jt, 0);
      ROUND(jt + 1, 1);
    }
    if (jt < ntiles) ROUND(jt, 0);                      // ntiles odd -> tail on buf0

    // epilogue: normalize by acc[4][0] (= sum P, any r), pack pairs, store bf16
    const float inv = 1.f / acc[4][0];
    const size_t rowO = (size_t)(b*T_SEQ + qg)*DM + h*DKH;
    #pragma unroll
    for (int mt = 0; mt < 4; ++mt){
      unsigned u0 = (unsigned)f2bfc(acc[mt][0]*inv) | ((unsigned)f2bfc(acc[mt][1]*inv) << 16);
      unsigned u1 = (unsigned)f2bfc(acc[mt][2]*inv) | ((unsigned)f2bfc(acc[mt][3]*inv) << 16);
      *(unsigned*)(Og + rowO + mt*16 + 4*g)     = u0;
      *(unsigned*)(Og + rowO + mt*16 + 4*g + 2) = u1;
    }
    // seg boundary: every ROUND ends with __syncthreads -> all reads of both
    // buffers are ordered before next segment's STAGE overwrites.
  }
#undef ROUND
}

// ---------------- launch ----------------
extern "C" void kernel_launch(void* const* d_in, const int* in_sizes, int n_in,
                              void* d_out, int out_size, void* d_ws, size_t ws_size,
                              hipStream_t stream)
{
  (void)in_sizes; (void)n_in; (void)out_size; (void)ws_size;
  const float* H  = (const float*)d_in[0];
  const float* Wq = (const float*)d_in[1];
  const float* Wk = (const float*)d_in[2];
  const float* Wv = (const float*)d_in[3];
  const float* Wo = (const float*)d_in[4];
  char* ws = (char*)d_ws;
  // ws layout (bytes): Hb 16MB | Wq^T|Wk^T (2048x1024) 4MB | Wv^T 2MB | Wo^T 2MB |
  // QK [8192][2048] 32MB | Vt 16MB | Ab 16MB = 88MB
  unsigned short* Hb   = (unsigned short*)(ws);
  unsigned short* Wqkt = (unsigned short*)(ws + 16777216);   // rows 0-1023: Wq^T (scaled), 1024-2047: Wk^T
  unsigned short* Wkt  = (unsigned short*)(ws + 18874368);
  unsigned short* Wvt  = (unsigned short*)(ws + 20971520);
  unsigned short* Wot  = (unsigned short*)(ws + 23068672);
  unsigned short* QKb  = (unsigned short*)(ws + 25165824);   // 32MB
  unsigned short* Vtb  = (unsigned short*)(ws + 58720256);
  unsigned short* Ab   = (unsigned short*)(ws + 75497472);

  convprep<<<6144, 256, 0, stream>>>(H, Wq, Wk, Wv, Wo,
                                     (u16x4*)Hb, Wqkt, Wkt, Wvt, Wot);
  gemm_qkv<<<1536, 256, 0, stream>>>(Hb, Wqkt, QKb, Wvt, Vtb);
  attn_kernel<<<dim3(512), 512, 0, stream>>>(QKb, Vtb, Ab);
  gemm_out<<<dim3(64,8), 256, 0, stream>>>(Ab, Wot, (float*)d_out);
}

// Round 10
// 154.245 us; speedup vs baseline: 1.4698x; 1.1100x over previous
//
#include <hip/hip_runtime.h>
#include <hip/hip_bf16.h>

#define T_SEQ 2048
#define DM 1024
#define DM2 2048
#define NH 16
#define DKH 64
#define NBATCH 4
#define MROWS (NBATCH*T_SEQ)   // 8192

typedef __attribute__((ext_vector_type(8))) short bf16x8;
typedef __attribute__((ext_vector_type(4))) short bf16x4;
typedef __attribute__((ext_vector_type(4))) float f32x4;
typedef __attribute__((ext_vector_type(16))) float f32x16;
typedef __attribute__((ext_vector_type(4))) unsigned short u16x4;

#define NEG_INF (-__builtin_inff())

#if __has_builtin(__builtin_amdgcn_exp2f)
#define EXP2(x) __builtin_amdgcn_exp2f(x)
#else
#define EXP2(x) exp2f(x)
#endif

#define MFMA32(A,B,C) __builtin_amdgcn_mfma_f32_32x32x16_bf16(A,B,C,0,0,0)

static __device__ __forceinline__ unsigned short f2bf(float f){
  union { float f; unsigned u; } v; v.f = f;
  unsigned r = v.u + 0x7fffu + ((v.u >> 16) & 1u);
  return (unsigned short)(r >> 16);
}

// RTNE float->bf16 via HW cvt (compiler fuses pairs into v_cvt_pk_bf16_f32, m240)
static __device__ __forceinline__ unsigned short f2bfc(float f){
  union { __hip_bfloat16 h; unsigned short u; } cv;
  cv.h = __float2bfloat16(f);
  return cv.u;
}

static __device__ __forceinline__ void gload_lds16(const void* g, void* l){
  __builtin_amdgcn_global_load_lds(
      (const __attribute__((address_space(1))) void*)g,
      (__attribute__((address_space(3))) void*)l, 16, 0, 0);
}

// ---------- fused prep: H fp32->bf16 (grid tail) + weight convert/transpose ----------
__global__ __launch_bounds__(256) void convprep(
    const float* __restrict__ H,
    const float* __restrict__ W0, const float* __restrict__ W1,
    const float* __restrict__ W2, const float* __restrict__ W3,
    u16x4* __restrict__ Hb4,
    unsigned short* __restrict__ O0, unsigned short* __restrict__ O1,
    unsigned short* __restrict__ O2, unsigned short* __restrict__ O3)
{
  __shared__ float t[32][33];
  const int bid = blockIdx.x, tid = threadIdx.x;
  if (bid < 4096){
    const int z = bid >> 10, rem = bid & 1023;
    const int nx = (rem & 31)*32, kx = (rem >> 5)*32;
    const float* W = (z==0)?W0:(z==1)?W1:(z==2)?W2:W3;
    unsigned short* O = (z==0)?O0:(z==1)?O1:(z==2)?O2:O3;
    const float sc = (z==0) ? 0.18033688f : 1.0f;   // log2e/8 folded into Wq
    const int tx = tid & 31, ty = tid >> 5;
    #pragma unroll
    for (int i = 0; i < 4; ++i)
      t[ty + i*8][tx] = W[(size_t)(kx + ty + i*8)*DM + nx + tx];
    __syncthreads();
    #pragma unroll
    for (int i = 0; i < 4; ++i)
      O[(size_t)(nx + ty + i*8)*DM + kx + tx] = f2bf(t[tx][ty + i*8] * sc);
  } else {
    const int n4 = MROWS*DM/4;
    for (int i = (bid - 4096)*256 + tid; i < n4; i += 2048*256){
      float4 v = ((const float4*)H)[i];
      u16x4 o;
      o[0] = f2bf(v.x); o[1] = f2bf(v.y); o[2] = f2bf(v.z); o[3] = f2bf(v.w);
      Hb4[i] = o;
    }
  }
}

// ---------------- GEMM core ----------------
// 128x128 tile, BK=64, 4 waves (2x2), 16x16x32 bf16 MFMA, global_load_lds staging,
// XOR-swizzled LDS ((row&7) chunk-XOR within 128B rows): conflict-free both sides.
template<bool F32OUT>
static __device__ __forceinline__ void gemm_body(
    const unsigned short* __restrict__ A, const unsigned short* __restrict__ Bt,
    void* __restrict__ Cp, int N, int K, int m0, int n0,
    unsigned short* a_lds, unsigned short* b_lds)
{
  const int tid = threadIdx.x;
  const int w = tid >> 6, l = tid & 63;
  const int g = l >> 4, lr = l & 15;
  const int wr = w >> 1, wc = w & 1;
  f32x4 acc[4][4] = {};
  const int nk = K >> 6;
  for (int ks = 0; ks < nk; ++ks){
    __syncthreads();
    const int k0 = ks << 6;
    #pragma unroll
    for (int i = 0; i < 4; ++i){
      int c = (w*4 + i)*64 + l;           // 0..1023, 16B chunks
      int row = c >> 3;
      int gc = (c & 7) ^ (row & 7);       // pre-swizzled global source (m173 pattern)
      gload_lds16(A + (size_t)(m0 + row)*K + (k0 + gc*8), &a_lds[c*8]);
    }
    #pragma unroll
    for (int i = 0; i < 4; ++i){
      int c = (w*4 + i)*64 + l;
      int row = c >> 3;
      int gc = (c & 7) ^ (row & 7);
      gload_lds16(Bt + (size_t)(n0 + row)*K + (k0 + gc*8), &b_lds[c*8]);
    }
    __syncthreads();
    #pragma unroll
    for (int kc = 0; kc < 2; ++kc){
      bf16x8 af[4], bf_[4];
      #pragma unroll
      for (int mt = 0; mt < 4; ++mt){
        int row = wr*64 + mt*16 + lr;
        int off = row*128 + ((kc*64 + g*16) ^ ((row & 7) << 4));
        af[mt] = *(const bf16x8*)((const char*)a_lds + off);
      }
      #pragma unroll
      for (int nt = 0; nt < 4; ++nt){
        int row = wc*64 + nt*16 + lr;
        int off = row*128 + ((kc*64 + g*16) ^ ((row & 7) << 4));
        bf_[nt] = *(const bf16x8*)((const char*)b_lds + off);
      }
      #pragma unroll
      for (int mt = 0; mt < 4; ++mt)
        #pragma unroll
        for (int nt = 0; nt < 4; ++nt)
          acc[mt][nt] = __builtin_amdgcn_mfma_f32_16x16x32_bf16(af[mt], bf_[nt], acc[mt][nt], 0, 0, 0);
    }
  }
  #pragma unroll
  for (int mt = 0; mt < 4; ++mt){
    #pragma unroll
    for (int nt = 0; nt < 4; ++nt){
      const int col = n0 + wc*64 + nt*16 + lr;
      #pragma unroll
      for (int r = 0; r < 4; ++r){
        const int row = m0 + wr*64 + mt*16 + 4*g + r;   // C/D: col=lane&15, row=(lane>>4)*4+r (m89)
        if (F32OUT) ((float*)Cp)[(size_t)row*N + col] = acc[mt][nt][r];
        else ((unsigned short*)Cp)[(size_t)row*N + col] = f2bf(acc[mt][nt][r]);
      }
    }
  }
}

// Fused QK-projection + V^T-projection dispatch.
__global__ __launch_bounds__(256) void gemm_qkv(
    const unsigned short* __restrict__ Hb, const unsigned short* __restrict__ Wqkt,
    unsigned short* __restrict__ QKb,
    const unsigned short* __restrict__ Wvt, unsigned short* __restrict__ Vtb)
{
  __shared__ __attribute__((aligned(16))) unsigned short a_lds[128*64];
  __shared__ __attribute__((aligned(16))) unsigned short b_lds[128*64];
  const int bid = blockIdx.x;
  const unsigned short *A, *Bt; unsigned short* Cp; int N, m0, n0;
  if (bid < 1024){
    A = Hb; Bt = Wqkt; Cp = QKb; N = DM2;
    m0 = (bid & 63)*128; n0 = (bid >> 6)*128;
  } else {
    const int t2 = bid - 1024;
    A = Wvt; Bt = Hb; Cp = Vtb; N = MROWS;
    m0 = (t2 & 7)*128; n0 = (t2 >> 3)*128;
  }
  gemm_body<false>(A, Bt, Cp, N, DM, m0, n0, a_lds, b_lds);
}

// Output GEMM: d_out[8192][1024] fp32 = Ab @ Wo^T
__global__ __launch_bounds__(256) void gemm_out(
    const unsigned short* __restrict__ Ab, const unsigned short* __restrict__ Wot,
    float* __restrict__ Out)
{
  __shared__ __attribute__((aligned(16))) unsigned short a_lds[128*64];
  __shared__ __attribute__((aligned(16))) unsigned short b_lds[128*64];
  gemm_body<true>(Ab, Wot, Out, DM, DM, blockIdx.x*128, blockIdx.y*128, a_lds, b_lds);
}

// ---- per-64kv-half softmax (exp2 domain; T13 defer-max THR=8; VALU denominator) ----
// st0/st1: S^T 32x32 D-tiles (two kv-tiles). Lane reg r of tile t holds
// kv = kvb + 32t + (r&3) + 4*((r>>2)&1) + 16*(r>>3)   [kvb includes +8*h1]
// exp'd in place; pb[jl] = B-frags for PV (pb[2t+m] = st_t regs 8m..8m+7).
static __device__ __forceinline__ void half_softmax(
    f32x16& st0, f32x16& st1, float& m_run, float& l_run,
    f32x16& acc0, f32x16& acc1, bf16x8 (&pb)[4],
    int kvb, int qg, bool fullT)
{
  if (!fullT){
    #pragma unroll
    for (int r = 0; r < 16; ++r){
      const int kvo = (r & 3) + 4*((r >> 2) & 1) + 16*(r >> 3);
      st0[r] = (kvb + kvo      <= qg) ? st0[r] : NEG_INF;
      st1[r] = (kvb + 32 + kvo <= qg) ? st1[r] : NEG_INF;
    }
  }
  float m01[8];
  #pragma unroll
  for (int r = 0; r < 8; ++r)
    m01[r] = fmaxf(fmaxf(st0[2*r], st0[2*r+1]), fmaxf(st1[2*r], st1[2*r+1]));
  float tm = fmaxf(fmaxf(fmaxf(m01[0],m01[1]), fmaxf(m01[2],m01[3])),
                   fmaxf(fmaxf(m01[4],m01[5]), fmaxf(m01[6],m01[7])));
  float mm = m_run;
  if (!__all(tm - m_run <= 8.f)){                 // NaN (first tile) -> false -> rescale path
    float tg = fmaxf(tm, __shfl_xor(tm, 32));
    const float mn = fmaxf(m_run, tg);
    const float fac = EXP2(m_run - mn);           // first tile: exp2(-inf)=0
    l_run *= fac;
    #pragma unroll
    for (int r = 0; r < 16; ++r){ acc0[r] *= fac; acc1[r] *= fac; }
    m_run = mn; mm = mn;
  }
  float ps0 = 0.f, ps1 = 0.f, ps2 = 0.f, ps3 = 0.f;
  #pragma unroll
  for (int r = 0; r < 4; ++r){
    float e0 = EXP2(st0[4*r+0]-mm), e1 = EXP2(st0[4*r+1]-mm);
    float e2 = EXP2(st0[4*r+2]-mm), e3 = EXP2(st0[4*r+3]-mm);
    float f0 = EXP2(st1[4*r+0]-mm), f1 = EXP2(st1[4*r+1]-mm);
    float f2 = EXP2(st1[4*r+2]-mm), f3 = EXP2(st1[4*r+3]-mm);
    ps0 += e0 + f0; ps1 += e1 + f1; ps2 += e2 + f2; ps3 += e3 + f3;
    st0[4*r+0]=e0; st0[4*r+1]=e1; st0[4*r+2]=e2; st0[4*r+3]=e3;
    st1[4*r+0]=f0; st1[4*r+1]=f1; st1[4*r+2]=f2; st1[4*r+3]=f3;
  }
  l_run += (ps0 + ps1) + (ps2 + ps3);             // lane-local partial; cross-half at epilogue
  #pragma unroll
  for (int m = 0; m < 2; ++m){
    bf16x8 t0, t1;
    #pragma unroll
    for (int i = 0; i < 8; ++i){
      t0[i] = (short)f2bfc(st0[8*m+i]);
      t1[i] = (short)f2bfc(st1[8*m+i]);
    }
    pb[m] = t0; pb[2+m] = t1;
  }
}

// ---------------- causal flash attention (32x32 MFMA) ----------------
// Grid: 256 linear; decode L -> xcd=L&7, idx=L>>3, bh=xcd*8+(idx&7), pair=idx>>3.
// Each block: TWO q-blocks (7-pair, then pair), QBLK=256 -> exactly 18 rounds
// per block: perfect static balance; XCD grouping keeps K/V L2-resident.
// Block: 8 waves x 512 thr; wave owns 32 q rows. KVBLK=128, double-buffered
// prefetch, one barrier per round, compile-time buffer parity (ntiles even).
// QK^T: S^T = mfma_32x32x16(K,Q). K rows placed in LDS via permutation sigma
// (kv -> D-row field mapping) so each lane's S regs are the CONTIGUOUS
// B-fragments PV needs (zero cross-lane movement). PV: O^T = V^T @ P^T, also
// 32x32x16 (full rate). Denominator: lane-local VALU partials + one
// shfl_xor(32) at epilogue. Q pre-scaled by log2e/sqrt(dk) via Wq.
// LDS: K [128 rows][64dk] swz(row&7); V [64dk][128kv] swz(row&15).
__global__ __launch_bounds__(512, 2) void attn_kernel(const unsigned short* __restrict__ QK,
                                                      const unsigned short* __restrict__ Vt,
                                                      unsigned short* __restrict__ Og)
{
  __shared__ __attribute__((aligned(16))) unsigned short k_lds[2][128*64];
  __shared__ __attribute__((aligned(16))) unsigned short v_lds[2][64*128];
  const int tid = threadIdx.x;
  const int w = tid >> 6, l = tid & 63;
  const int h1 = l >> 5, lq = l & 31;                   // half-wave, row/col lane index
  const int L = blockIdx.x;
  const int xcd = L & 7, idx = L >> 3;
  const int bh = xcd*8 + (idx & 7);
  const int pair = idx >> 3;                            // 0..3
  const int b = bh >> 4, h = bh & 15;
  const size_t baseK = (size_t)(b*T_SEQ)*DM2 + 1024 + h*DKH;    // K rows in QK [t][2048]
  const size_t baseV = (size_t)(h*DKH)*MROWS + (size_t)b*T_SEQ; // Vt rows [n][t]

  // K staging: LDS row rho holds K[kv = j0 + kappa(rho)] (sigma placement).
  // kappa(rho): r32=rho&31: a=r32&3, hh=(r32>>2)&1, bb=r32>>3:
  //   kappa = 32*(rho>>5) + 16*(bb>>1) + 8*hh + 4*(bb&1) + a     (bijective)
  const int cA = tid, cB = tid + 512;                   // 16B chunk ids
  const int krA = cA >> 3, krB = cB >> 3;
  const int kiA = (cA & 7) ^ (krA & 7), kiB = (cB & 7) ^ (krB & 7);
  const int kvA = 32*(krA >> 5) + 16*((krA >> 4) & 1) + 8*((krA >> 2) & 1) + 4*((krA >> 3) & 1) + (krA & 3);
  const int kvB = 32*(krB >> 5) + 16*((krB >> 4) & 1) + 8*((krB >> 2) & 1) + 4*((krB >> 3) & 1) + (krB & 3);
  const int vrA = cA >> 4, vgA = (cA & 15) ^ (vrA & 15);
  const int vrB = cB >> 4, vgB = (cB & 15) ^ (vrB & 15);

  auto STAGE = [&](int jt, int buf){
    const int j0s = jt * 128;
    gload_lds16(QK + baseK + (size_t)(j0s + kvA)*DM2 + kiA*8, &k_lds[buf][cA*8]);
    gload_lds16(QK + baseK + (size_t)(j0s + kvB)*DM2 + kiB*8, &k_lds[buf][cB*8]);
    gload_lds16(Vt + baseV + (size_t)vrA*MROWS + j0s + vgA*8, &v_lds[buf][cA*8]);
    gload_lds16(Vt + baseV + (size_t)vrB*MROWS + j0s + vgB*8, &v_lds[buf][cB*8]);
  };

#define ROUND(JT, CUR) do{                                                        \
    const int jt_ = (JT);                                                         \
    if (jt_ + 1 < ntiles) STAGE(jt_ + 1, (CUR)^1);                                \
    const int j0_ = jt_ * 128;                                                    \
    _Pragma("unroll")                                                             \
    for (int h2 = 0; h2 < 2; ++h2){                                               \
      if (j0_ + 64*h2 <= qhi){                                                    \
        f32x16 st0 = {}, st1 = {};                                                \
        __builtin_amdgcn_s_setprio(1);                                            \
        _Pragma("unroll")                                                         \
        for (int s = 0; s < 4; ++s){                                              \
          const int r0_ = 64*h2 + lq, r1_ = r0_ + 32;                             \
          bf16x8 kf0 = *(const bf16x8*)((const char*)k_lds[CUR] + r0_*128 + (((2*s + h1) ^ (r0_ & 7)) << 4)); \
          bf16x8 kf1 = *(const bf16x8*)((const char*)k_lds[CUR] + r1_*128 + (((2*s + h1) ^ (r1_ & 7)) << 4)); \
          st0 = MFMA32(kf0, qf[s], st0);                                          \
          st1 = MFMA32(kf1, qf[s], st1);                                          \
        }                                                                         \
        __builtin_amdgcn_s_setprio(0);                                            \
        bf16x8 pb[4];                                                             \
        half_softmax(st0, st1, m_run, l_run, acc0, acc1, pb,                      \
                     j0_ + 64*h2 + 8*h1, qg, (j0_ + 64*h2 + 63) <= qlo);          \
        __builtin_amdgcn_s_setprio(1);                                            \
        _Pragma("unroll")                                                         \
        for (int jl = 0; jl < 4; ++jl){                                           \
          const int vr0 = lq, vr1 = 32 + lq;                                      \
          bf16x8 vf0 = *(const bf16x8*)((const char*)v_lds[CUR] + vr0*256 + (((2*(4*h2 + jl) + h1) ^ (vr0 & 15)) << 4)); \
          bf16x8 vf1 = *(const bf16x8*)((const char*)v_lds[CUR] + vr1*256 + (((2*(4*h2 + jl) + h1) ^ (vr1 & 15)) << 4)); \
          acc0 = MFMA32(vf0, pb[jl], acc0);                                       \
          acc1 = MFMA32(vf1, pb[jl], acc1);                                       \
        }                                                                         \
        __builtin_amdgcn_s_setprio(0);                                            \
      }                                                                           \
    }                                                                             \
    __syncthreads();                                                              \
  } while(0)

  #pragma unroll 1
  for (int seg = 0; seg < 2; ++seg){
    const int qblk = seg ? pair : (7 - pair);           // heavy then light: 18 rounds total
    const int q0 = qblk * 256;
    const int qlo = q0 + 32*w;
    const int qhi = qlo + 31;
    const int qg = qlo + lq;                            // this lane's q row
    const size_t rowQ = (size_t)(b*T_SEQ + qg)*DM2 + h*DKH;
    bf16x8 qf[4];
    #pragma unroll
    for (int s = 0; s < 4; ++s)
      qf[s] = *(const bf16x8*)(QK + rowQ + 16*s + 8*h1);
    float m_run = NEG_INF, l_run = 0.f;
    f32x16 acc0 = {}, acc1 = {};                        // O^T dk-tiles 0,1 (D-layout)
    const int ntiles = 2*qblk + 2;                      // even -> clean buffer pairing

    STAGE(0, 0);
    __syncthreads();                                    // drains vmcnt -> buf0 ready

    #pragma unroll 1
    for (int jt = 0; jt < ntiles; jt += 2){
      ROUND(jt, 0);
      ROUND(jt + 1, 1);
    }

    // epilogue: combine denominator halves, normalize, pack, store bf16
    const float ls = l_run + __shfl_xor(l_run, 32);
    const float inv = 1.f / ls;
    const size_t rowO = (size_t)(b*T_SEQ + qg)*DM + h*DKH;
    #pragma unroll
    for (int d = 0; d < 2; ++d){
      const f32x16& A = d ? acc1 : acc0;
      #pragma unroll
      for (int bb = 0; bb < 4; ++bb){
        unsigned u0 = (unsigned)f2bfc(A[4*bb+0]*inv) | ((unsigned)f2bfc(A[4*bb+1]*inv) << 16);
        unsigned u1 = (unsigned)f2bfc(A[4*bb+2]*inv) | ((unsigned)f2bfc(A[4*bb+3]*inv) << 16);
        uint2 uv; uv.x = u0; uv.y = u1;
        *(uint2*)(Og + rowO + 32*d + 8*bb + 4*h1) = uv; // dk = 32d+8bb+4h1 + (0..3)
      }
    }
    // seg boundary: ROUND ends with __syncthreads -> safe to re-STAGE buf0.
  }
#undef ROUND
}

// ---------------- launch ----------------
extern "C" void kernel_launch(void* const* d_in, const int* in_sizes, int n_in,
                              void* d_out, int out_size, void* d_ws, size_t ws_size,
                              hipStream_t stream)
{
  (void)in_sizes; (void)n_in; (void)out_size; (void)ws_size;
  const float* H  = (const float*)d_in[0];
  const float* Wq = (const float*)d_in[1];
  const float* Wk = (const float*)d_in[2];
  const float* Wv = (const float*)d_in[3];
  const float* Wo = (const float*)d_in[4];
  char* ws = (char*)d_ws;
  // ws layout (bytes): Hb 16MB | Wq^T|Wk^T (2048x1024) 4MB | Wv^T 2MB | Wo^T 2MB |
  // QK [8192][2048] 32MB | Vt 16MB | Ab 16MB = 88MB
  unsigned short* Hb   = (unsigned short*)(ws);
  unsigned short* Wqkt = (unsigned short*)(ws + 16777216);   // rows 0-1023: Wq^T (scaled), 1024-2047: Wk^T
  unsigned short* Wkt  = (unsigned short*)(ws + 18874368);
  unsigned short* Wvt  = (unsigned short*)(ws + 20971520);
  unsigned short* Wot  = (unsigned short*)(ws + 23068672);
  unsigned short* QKb  = (unsigned short*)(ws + 25165824);   // 32MB
  unsigned short* Vtb  = (unsigned short*)(ws + 58720256);
  unsigned short* Ab   = (unsigned short*)(ws + 75497472);

  convprep<<<6144, 256, 0, stream>>>(H, Wq, Wk, Wv, Wo,
                                     (u16x4*)Hb, Wqkt, Wkt, Wvt, Wot);
  gemm_qkv<<<1536, 256, 0, stream>>>(Hb, Wqkt, QKb, Wvt, Vtb);
  attn_kernel<<<dim3(256), 512, 0, stream>>>(QKb, Vtb, Ab);
  gemm_out<<<dim3(64,8), 256, 0, stream>>>(Ab, Wot, (float*)d_out);
}

// Round 11
// 152.528 us; speedup vs baseline: 1.4863x; 1.0113x over previous
//
#include <hip/hip_runtime.h>
#include <hip/hip_bf16.h>

#define T_SEQ 2048
#define DM 1024
#define DM2 2048
#define NH 16
#define DKH 64
#define NBATCH 4
#define MROWS (NBATCH*T_SEQ)   // 8192

typedef __attribute__((ext_vector_type(8))) short bf16x8;
typedef __attribute__((ext_vector_type(4))) short bf16x4;
typedef __attribute__((ext_vector_type(4))) float f32x4;
typedef __attribute__((ext_vector_type(16))) float f32x16;
typedef __attribute__((ext_vector_type(4))) unsigned short u16x4;

#define NEG_INF (-__builtin_inff())

#if __has_builtin(__builtin_amdgcn_exp2f)
#define EXP2(x) __builtin_amdgcn_exp2f(x)
#else
#define EXP2(x) exp2f(x)
#endif

#define MFMA32(A,B,C) __builtin_amdgcn_mfma_f32_32x32x16_bf16(A,B,C,0,0,0)

static __device__ __forceinline__ unsigned short f2bf(float f){
  union { float f; unsigned u; } v; v.f = f;
  unsigned r = v.u + 0x7fffu + ((v.u >> 16) & 1u);
  return (unsigned short)(r >> 16);
}

// RTNE float->bf16 via HW cvt (compiler fuses pairs into v_cvt_pk_bf16_f32, m240)
static __device__ __forceinline__ unsigned short f2bfc(float f){
  union { __hip_bfloat16 h; unsigned short u; } cv;
  cv.h = __float2bfloat16(f);
  return cv.u;
}

static __device__ __forceinline__ void gload_lds16(const void* g, void* l){
  __builtin_amdgcn_global_load_lds(
      (const __attribute__((address_space(1))) void*)g,
      (__attribute__((address_space(3))) void*)l, 16, 0, 0);
}

// ---------- fused prep: H fp32->bf16 (grid tail) + weight convert/transpose ----------
__global__ __launch_bounds__(256) void convprep(
    const float* __restrict__ H,
    const float* __restrict__ W0, const float* __restrict__ W1,
    const float* __restrict__ W2, const float* __restrict__ W3,
    u16x4* __restrict__ Hb4,
    unsigned short* __restrict__ O0, unsigned short* __restrict__ O1,
    unsigned short* __restrict__ O2, unsigned short* __restrict__ O3)
{
  __shared__ float t[32][33];
  const int bid = blockIdx.x, tid = threadIdx.x;
  if (bid < 4096){
    const int z = bid >> 10, rem = bid & 1023;
    const int nx = (rem & 31)*32, kx = (rem >> 5)*32;
    const float* W = (z==0)?W0:(z==1)?W1:(z==2)?W2:W3;
    unsigned short* O = (z==0)?O0:(z==1)?O1:(z==2)?O2:O3;
    const float sc = (z==0) ? 0.18033688f : 1.0f;   // log2e/8 folded into Wq
    const int tx = tid & 31, ty = tid >> 5;
    #pragma unroll
    for (int i = 0; i < 4; ++i)
      t[ty + i*8][tx] = W[(size_t)(kx + ty + i*8)*DM + nx + tx];
    __syncthreads();
    #pragma unroll
    for (int i = 0; i < 4; ++i)
      O[(size_t)(nx + ty + i*8)*DM + kx + tx] = f2bf(t[tx][ty + i*8] * sc);
  } else {
    const int n4 = MROWS*DM/4;
    for (int i = (bid - 4096)*256 + tid; i < n4; i += 2048*256){
      float4 v = ((const float4*)H)[i];
      u16x4 o;
      o[0] = f2bf(v.x); o[1] = f2bf(v.y); o[2] = f2bf(v.z); o[3] = f2bf(v.w);
      Hb4[i] = o;
    }
  }
}

// ---------------- 8-phase 256x256 GEMM (T3+T4+T5): QK projection ----------------
// C[8192][2048] = A[8192][1024] @ Bt[2048][1024]^T. Grid 256 = 1 block/CU.
// 8 waves (2M x 4N), per-wave C = 128x64 (8mt x 4nt 16x16 frags). BK=64.
// LDS 128KB: 2 bufs x {A 256x64 (2 halves), B 256x64 (2 halves)}.
// Per phase: ds_read one reg quadrant + stage one half-tile (2 gloads/thr)
// + barrier + lgkmcnt(0) + 16 MFMA + barrier. Counted vmcnt(4) ONLY before
// the trailing barrier of ph4/ph8 (publishes the buffer the next half-iter
// reads; per-wave vmcnt then barrier = cross-wave visibility).
// Stage slots (iter i): ph1:buf1.A0<-t(2i+1) ph2:buf1.A1 ph3:buf0.B0<-t(2i+2)
// ph4:buf0.B1 ph5:buf0.A0 ph6:buf0.A1 ph7:buf1.B0<-t(2i+3) ph8:buf1.B1.
// Each region staged >=1 phase after its last LDS read (WAR-safe via barriers).
// Swizzle: chunk-XOR (row&7) both sides (verified 0 bank conflicts in R10).
__global__ __launch_bounds__(512, 2) void gemm_qk8(
    const unsigned short* __restrict__ A, const unsigned short* __restrict__ Bt,
    unsigned short* __restrict__ C)
{
  __shared__ __attribute__((aligned(16))) unsigned short lds[2][32768]; // 128 KiB
  const int tid = threadIdx.x;
  const int w = tid >> 6, l = tid & 63;
  const int g = l >> 4, lr = l & 15;
  const int wr = w >> 2, wc = w & 3;
  const int bid = blockIdx.x;
  const int m0 = (bid & 31) * 256, n0 = (bid >> 5) * 256;  // m-grouped per XCD

  // staging: 1024 chunks/half-tile; thread does 2 (16B each)
  const int c0 = (w*2)*64 + l, c1 = (w*2+1)*64 + l;
  const int r0 = c0 >> 3, gc0 = (c0 & 7) ^ (r0 & 7);
  const int r1 = c1 >> 3, gc1 = (c1 & 7) ^ (r1 & 7);

  auto STA = [&](int h, int t, int buf){   // A-half h of K-tile t -> buf
    gload_lds16(A + (size_t)(m0 + h*128 + r0)*DM + t*64 + gc0*8,
                (char*)lds + buf*65536 + h*16384 + c0*16);
    gload_lds16(A + (size_t)(m0 + h*128 + r1)*DM + t*64 + gc1*8,
                (char*)lds + buf*65536 + h*16384 + c1*16);
  };
  auto STB = [&](int h, int t, int buf){   // B-half h of K-tile t -> buf
    gload_lds16(Bt + (size_t)(n0 + h*128 + r0)*DM + t*64 + gc0*8,
                (char*)lds + buf*65536 + 32768 + h*16384 + c0*16);
    gload_lds16(Bt + (size_t)(n0 + h*128 + r1)*DM + t*64 + gc1*8,
                (char*)lds + buf*65536 + 32768 + h*16384 + c1*16);
  };

  f32x4 acc[8][4] = {};
  bf16x8 af[8], bf[8];

  // prologue: tile0 -> buf0, tile1 -> buf1; publish buf0
  STB(0,0,0); STB(1,0,0); STA(0,0,0); STA(1,0,0);
  STB(0,1,1); STB(1,1,1); STA(0,1,1); STA(1,1,1);
  asm volatile("s_waitcnt vmcnt(8)");
  __builtin_amdgcn_s_barrier();

#define RDA(BUF, MH) do{ _Pragma("unroll") for (int mi=0;mi<4;++mi){            \
    const int ra = ((MH)*4+mi)*16 + lr;                                         \
    _Pragma("unroll") for (int kc=0;kc<2;++kc)                                  \
      af[mi*2+kc] = *(const bf16x8*)((const char*)lds + (BUF)*65536             \
        + wr*16384 + ra*128 + ((kc*64+g*16) ^ ((ra&7)<<4))); } }while(0)
#define RDB(BUF, NHI) do{ _Pragma("unroll") for (int ni=0;ni<2;++ni){           \
    const int nt = (NHI)*2+ni; const int rb = (wc&1)*64 + nt*16 + lr;           \
    _Pragma("unroll") for (int kc=0;kc<2;++kc)                                  \
      bf[nt*2+kc] = *(const bf16x8*)((const char*)lds + (BUF)*65536 + 32768     \
        + (wc>>1)*16384 + rb*128 + ((kc*64+g*16) ^ ((rb&7)<<4))); } }while(0)
#define MF(MH, NHI) do{ _Pragma("unroll") for (int mi=0;mi<4;++mi)              \
    _Pragma("unroll") for (int ni=0;ni<2;++ni)                                  \
    _Pragma("unroll") for (int kc=0;kc<2;++kc)                                  \
      acc[(MH)*4+mi][(NHI)*2+ni] = __builtin_amdgcn_mfma_f32_16x16x32_bf16(     \
        af[mi*2+kc], bf[((NHI)*2+ni)*2+kc], acc[(MH)*4+mi][(NHI)*2+ni],0,0,0); }while(0)
#define WAITL0 do{ asm volatile("s_waitcnt lgkmcnt(0)");                        \
    __builtin_amdgcn_sched_barrier(0); }while(0)

  #pragma unroll 1
  for (int i = 0; i < 8; ++i){
    const int t1 = 2*i+1, t2 = 2*i+2, t3 = 2*i+3;
    // ---- ph1: buf0 quadrant (m0,n01) ----
    RDA(0,0); RDB(0,0);
    if (i > 0) STA(0, t1, 1);
    asm volatile("s_waitcnt lgkmcnt(8)");
    __builtin_amdgcn_s_barrier();
    WAITL0;
    __builtin_amdgcn_s_setprio(1); MF(0,0); __builtin_amdgcn_s_setprio(0);
    __builtin_amdgcn_s_barrier();
    // ---- ph2: (m0,n23) ----
    RDB(0,1);
    if (i > 0) STA(1, t1, 1);
    __builtin_amdgcn_s_barrier();
    WAITL0;
    __builtin_amdgcn_s_setprio(1); MF(0,1); __builtin_amdgcn_s_setprio(0);
    __builtin_amdgcn_s_barrier();
    // ---- ph3: (m1,n23) ----
    RDA(0,1);
    if (i < 7) STB(0, t2, 0);
    __builtin_amdgcn_s_barrier();
    WAITL0;
    __builtin_amdgcn_s_setprio(1); MF(1,1); __builtin_amdgcn_s_setprio(0);
    __builtin_amdgcn_s_barrier();
    // ---- ph4: (m1,n01), no reads; vmcnt publishes buf1 for ph5 ----
    if (i < 7) STB(1, t2, 0);
    __builtin_amdgcn_s_setprio(1); MF(1,0); __builtin_amdgcn_s_setprio(0);
    if (i < 7) asm volatile("s_waitcnt vmcnt(4)");
    else       asm volatile("s_waitcnt vmcnt(0)");   // last iter: ph1/2 stages are newest
    __builtin_amdgcn_s_barrier();
    // ---- ph5: buf1 quadrant (m0,n01) ----
    RDA(1,0); RDB(1,0);
    if (i < 7) STA(0, t2, 0);
    asm volatile("s_waitcnt lgkmcnt(8)");
    __builtin_amdgcn_s_barrier();
    WAITL0;
    __builtin_amdgcn_s_setprio(1); MF(0,0); __builtin_amdgcn_s_setprio(0);
    __builtin_amdgcn_s_barrier();
    // ---- ph6: (m0,n23) ----
    RDB(1,1);
    if (i < 7) STA(1, t2, 0);
    __builtin_amdgcn_s_barrier();
    WAITL0;
    __builtin_amdgcn_s_setprio(1); MF(0,1); __builtin_amdgcn_s_setprio(0);
    __builtin_amdgcn_s_barrier();
    // ---- ph7: (m1,n23) ----
    RDA(1,1);
    if (i < 7) STB(0, t3, 1);
    __builtin_amdgcn_s_barrier();
    WAITL0;
    __builtin_amdgcn_s_setprio(1); MF(1,1); __builtin_amdgcn_s_setprio(0);
    __builtin_amdgcn_s_barrier();
    // ---- ph8: (m1,n01); vmcnt publishes buf0 for next ph1 ----
    if (i < 7) STB(1, t3, 1);
    __builtin_amdgcn_s_setprio(1); MF(1,0); __builtin_amdgcn_s_setprio(0);
    asm volatile("s_waitcnt vmcnt(4)");
    __builtin_amdgcn_s_barrier();
  }
#undef RDA
#undef RDB
#undef MF
#undef WAITL0

  // epilogue: C/D layout m89: col=lane&15, row=(lane>>4)*4+r
  #pragma unroll
  for (int mt = 0; mt < 8; ++mt){
    const int row_b = m0 + wr*128 + mt*16 + 4*g;
    #pragma unroll
    for (int nt = 0; nt < 4; ++nt){
      const int col = n0 + wc*64 + nt*16 + lr;
      #pragma unroll
      for (int r = 0; r < 4; ++r)
        C[(size_t)(row_b + r)*DM2 + col] = f2bf(acc[mt][nt][r]);
    }
  }
}

// ---------------- 128x128 2-phase GEMM core (Vt + output GEMMs) ----------------
template<bool F32OUT>
static __device__ __forceinline__ void gemm_body(
    const unsigned short* __restrict__ A, const unsigned short* __restrict__ Bt,
    void* __restrict__ Cp, int N, int K, int m0, int n0,
    unsigned short* a_lds, unsigned short* b_lds)
{
  const int tid = threadIdx.x;
  const int w = tid >> 6, l = tid & 63;
  const int g = l >> 4, lr = l & 15;
  const int wr = w >> 1, wc = w & 1;
  f32x4 acc[4][4] = {};
  const int nk = K >> 6;
  for (int ks = 0; ks < nk; ++ks){
    __syncthreads();
    const int k0 = ks << 6;
    #pragma unroll
    for (int i = 0; i < 4; ++i){
      int c = (w*4 + i)*64 + l;
      int row = c >> 3;
      int gc = (c & 7) ^ (row & 7);
      gload_lds16(A + (size_t)(m0 + row)*K + (k0 + gc*8), &a_lds[c*8]);
    }
    #pragma unroll
    for (int i = 0; i < 4; ++i){
      int c = (w*4 + i)*64 + l;
      int row = c >> 3;
      int gc = (c & 7) ^ (row & 7);
      gload_lds16(Bt + (size_t)(n0 + row)*K + (k0 + gc*8), &b_lds[c*8]);
    }
    __syncthreads();
    #pragma unroll
    for (int kc = 0; kc < 2; ++kc){
      bf16x8 af[4], bf_[4];
      #pragma unroll
      for (int mt = 0; mt < 4; ++mt){
        int row = wr*64 + mt*16 + lr;
        int off = row*128 + ((kc*64 + g*16) ^ ((row & 7) << 4));
        af[mt] = *(const bf16x8*)((const char*)a_lds + off);
      }
      #pragma unroll
      for (int nt = 0; nt < 4; ++nt){
        int row = wc*64 + nt*16 + lr;
        int off = row*128 + ((kc*64 + g*16) ^ ((row & 7) << 4));
        bf_[nt] = *(const bf16x8*)((const char*)b_lds + off);
      }
      #pragma unroll
      for (int mt = 0; mt < 4; ++mt)
        #pragma unroll
        for (int nt = 0; nt < 4; ++nt)
          acc[mt][nt] = __builtin_amdgcn_mfma_f32_16x16x32_bf16(af[mt], bf_[nt], acc[mt][nt], 0, 0, 0);
    }
  }
  #pragma unroll
  for (int mt = 0; mt < 4; ++mt){
    #pragma unroll
    for (int nt = 0; nt < 4; ++nt){
      const int col = n0 + wc*64 + nt*16 + lr;
      #pragma unroll
      for (int r = 0; r < 4; ++r){
        const int row = m0 + wr*64 + mt*16 + 4*g + r;
        if (F32OUT) ((float*)Cp)[(size_t)row*N + col] = acc[mt][nt][r];
        else ((unsigned short*)Cp)[(size_t)row*N + col] = f2bf(acc[mt][nt][r]);
      }
    }
  }
}

// V^T projection: Vt[1024][8192] = Wvt @ Hb^T
__global__ __launch_bounds__(256) void gemm_vt(
    const unsigned short* __restrict__ Wvt, const unsigned short* __restrict__ Hb,
    unsigned short* __restrict__ Vtb)
{
  __shared__ __attribute__((aligned(16))) unsigned short a_lds[128*64];
  __shared__ __attribute__((aligned(16))) unsigned short b_lds[128*64];
  gemm_body<false>(Wvt, Hb, Vtb, MROWS, DM, blockIdx.x*128, blockIdx.y*128, a_lds, b_lds);
}

// Output GEMM: d_out[8192][1024] fp32 = Ab @ Wo^T
__global__ __launch_bounds__(256) void gemm_out(
    const unsigned short* __restrict__ Ab, const unsigned short* __restrict__ Wot,
    float* __restrict__ Out)
{
  __shared__ __attribute__((aligned(16))) unsigned short a_lds[128*64];
  __shared__ __attribute__((aligned(16))) unsigned short b_lds[128*64];
  gemm_body<true>(Ab, Wot, Out, DM, DM, blockIdx.x*128, blockIdx.y*128, a_lds, b_lds);
}

// ---- per-64kv-half softmax (exp2 domain; T13 defer-max THR=8; VALU denominator) ----
static __device__ __forceinline__ void half_softmax(
    f32x16& st0, f32x16& st1, float& m_run, float& l_run,
    f32x16& acc0, f32x16& acc1, bf16x8 (&pb)[4],
    int kvb, int qg, bool fullT)
{
  if (!fullT){
    #pragma unroll
    for (int r = 0; r < 16; ++r){
      const int kvo = (r & 3) + 4*((r >> 2) & 1) + 16*(r >> 3);
      st0[r] = (kvb + kvo      <= qg) ? st0[r] : NEG_INF;
      st1[r] = (kvb + 32 + kvo <= qg) ? st1[r] : NEG_INF;
    }
  }
  float m01[8];
  #pragma unroll
  for (int r = 0; r < 8; ++r)
    m01[r] = fmaxf(fmaxf(st0[2*r], st0[2*r+1]), fmaxf(st1[2*r], st1[2*r+1]));
  float tm = fmaxf(fmaxf(fmaxf(m01[0],m01[1]), fmaxf(m01[2],m01[3])),
                   fmaxf(fmaxf(m01[4],m01[5]), fmaxf(m01[6],m01[7])));
  float mm = m_run;
  if (!__all(tm - m_run <= 8.f)){                 // first tile: NaN -> rescale path
    float tg = fmaxf(tm, __shfl_xor(tm, 32));
    const float mn = fmaxf(m_run, tg);
    const float fac = EXP2(m_run - mn);           // first tile: exp2(-inf)=0
    l_run *= fac;
    #pragma unroll
    for (int r = 0; r < 16; ++r){ acc0[r] *= fac; acc1[r] *= fac; }
    m_run = mn; mm = mn;
  }
  float ps0 = 0.f, ps1 = 0.f, ps2 = 0.f, ps3 = 0.f;
  #pragma unroll
  for (int r = 0; r < 4; ++r){
    float e0 = EXP2(st0[4*r+0]-mm), e1 = EXP2(st0[4*r+1]-mm);
    float e2 = EXP2(st0[4*r+2]-mm), e3 = EXP2(st0[4*r+3]-mm);
    float f0 = EXP2(st1[4*r+0]-mm), f1 = EXP2(st1[4*r+1]-mm);
    float f2 = EXP2(st1[4*r+2]-mm), f3 = EXP2(st1[4*r+3]-mm);
    ps0 += e0 + f0; ps1 += e1 + f1; ps2 += e2 + f2; ps3 += e3 + f3;
    st0[4*r+0]=e0; st0[4*r+1]=e1; st0[4*r+2]=e2; st0[4*r+3]=e3;
    st1[4*r+0]=f0; st1[4*r+1]=f1; st1[4*r+2]=f2; st1[4*r+3]=f3;
  }
  l_run += (ps0 + ps1) + (ps2 + ps3);
  #pragma unroll
  for (int m = 0; m < 2; ++m){
    bf16x8 t0, t1;
    #pragma unroll
    for (int i = 0; i < 8; ++i){
      t0[i] = (short)f2bfc(st0[8*m+i]);
      t1[i] = (short)f2bfc(st1[8*m+i]);
    }
    pb[m] = t0; pb[2+m] = t1;
  }
}

// ---------------- causal flash attention (32x32 MFMA) — unchanged from R10 ----------------
__global__ __launch_bounds__(512, 2) void attn_kernel(const unsigned short* __restrict__ QK,
                                                      const unsigned short* __restrict__ Vt,
                                                      unsigned short* __restrict__ Og)
{
  __shared__ __attribute__((aligned(16))) unsigned short k_lds[2][128*64];
  __shared__ __attribute__((aligned(16))) unsigned short v_lds[2][64*128];
  const int tid = threadIdx.x;
  const int w = tid >> 6, l = tid & 63;
  const int h1 = l >> 5, lq = l & 31;
  const int L = blockIdx.x;
  const int xcd = L & 7, idx = L >> 3;
  const int bh = xcd*8 + (idx & 7);
  const int pair = idx >> 3;                            // 0..3
  const int b = bh >> 4, h = bh & 15;
  const size_t baseK = (size_t)(b*T_SEQ)*DM2 + 1024 + h*DKH;
  const size_t baseV = (size_t)(h*DKH)*MROWS + (size_t)b*T_SEQ;

  const int cA = tid, cB = tid + 512;
  const int krA = cA >> 3, krB = cB >> 3;
  const int kiA = (cA & 7) ^ (krA & 7), kiB = (cB & 7) ^ (krB & 7);
  const int kvA = 32*(krA >> 5) + 16*((krA >> 4) & 1) + 8*((krA >> 2) & 1) + 4*((krA >> 3) & 1) + (krA & 3);
  const int kvB = 32*(krB >> 5) + 16*((krB >> 4) & 1) + 8*((krB >> 2) & 1) + 4*((krB >> 3) & 1) + (krB & 3);
  const int vrA = cA >> 4, vgA = (cA & 15) ^ (vrA & 15);
  const int vrB = cB >> 4, vgB = (cB & 15) ^ (vrB & 15);

  auto STAGE = [&](int jt, int buf){
    const int j0s = jt * 128;
    gload_lds16(QK + baseK + (size_t)(j0s + kvA)*DM2 + kiA*8, &k_lds[buf][cA*8]);
    gload_lds16(QK + baseK + (size_t)(j0s + kvB)*DM2 + kiB*8, &k_lds[buf][cB*8]);
    gload_lds16(Vt + baseV + (size_t)vrA*MROWS + j0s + vgA*8, &v_lds[buf][cA*8]);
    gload_lds16(Vt + baseV + (size_t)vrB*MROWS + j0s + vgB*8, &v_lds[buf][cB*8]);
  };

#define ROUND(JT, CUR) do{                                                        \
    const int jt_ = (JT);                                                         \
    if (jt_ + 1 < ntiles) STAGE(jt_ + 1, (CUR)^1);                                \
    const int j0_ = jt_ * 128;                                                    \
    _Pragma("unroll")                                                             \
    for (int h2 = 0; h2 < 2; ++h2){                                               \
      if (j0_ + 64*h2 <= qhi){                                                    \
        f32x16 st0 = {}, st1 = {};                                                \
        __builtin_amdgcn_s_setprio(1);                                            \
        _Pragma("unroll")                                                         \
        for (int s = 0; s < 4; ++s){                                              \
          const int r0_ = 64*h2 + lq, r1_ = r0_ + 32;                             \
          bf16x8 kf0 = *(const bf16x8*)((const char*)k_lds[CUR] + r0_*128 + (((2*s + h1) ^ (r0_ & 7)) << 4)); \
          bf16x8 kf1 = *(const bf16x8*)((const char*)k_lds[CUR] + r1_*128 + (((2*s + h1) ^ (r1_ & 7)) << 4)); \
          st0 = MFMA32(kf0, qf[s], st0);                                          \
          st1 = MFMA32(kf1, qf[s], st1);                                          \
        }                                                                         \
        __builtin_amdgcn_s_setprio(0);                                            \
        bf16x8 pb[4];                                                             \
        half_softmax(st0, st1, m_run, l_run, acc0, acc1, pb,                      \
                     j0_ + 64*h2 + 8*h1, qg, (j0_ + 64*h2 + 63) <= qlo);          \
        __builtin_amdgcn_s_setprio(1);                                            \
        _Pragma("unroll")                                                         \
        for (int jl = 0; jl < 4; ++jl){                                           \
          const int vr0 = lq, vr1 = 32 + lq;                                      \
          bf16x8 vf0 = *(const bf16x8*)((const char*)v_lds[CUR] + vr0*256 + (((2*(4*h2 + jl) + h1) ^ (vr0 & 15)) << 4)); \
          bf16x8 vf1 = *(const bf16x8*)((const char*)v_lds[CUR] + vr1*256 + (((2*(4*h2 + jl) + h1) ^ (vr1 & 15)) << 4)); \
          acc0 = MFMA32(vf0, pb[jl], acc0);                                       \
          acc1 = MFMA32(vf1, pb[jl], acc1);                                       \
        }                                                                         \
        __builtin_amdgcn_s_setprio(0);                                            \
      }                                                                           \
    }                                                                             \
    __syncthreads();                                                              \
  } while(0)

  #pragma unroll 1
  for (int seg = 0; seg < 2; ++seg){
    const int qblk = seg ? pair : (7 - pair);
    const int q0 = qblk * 256;
    const int qlo = q0 + 32*w;
    const int qhi = qlo + 31;
    const int qg = qlo + lq;
    const size_t rowQ = (size_t)(b*T_SEQ + qg)*DM2 + h*DKH;
    bf16x8 qf[4];
    #pragma unroll
    for (int s = 0; s < 4; ++s)
      qf[s] = *(const bf16x8*)(QK + rowQ + 16*s + 8*h1);
    float m_run = NEG_INF, l_run = 0.f;
    f32x16 acc0 = {}, acc1 = {};
    const int ntiles = 2*qblk + 2;

    STAGE(0, 0);
    __syncthreads();

    #pragma unroll 1
    for (int jt = 0; jt < ntiles; jt += 2){
      ROUND(jt, 0);
      ROUND(jt + 1, 1);
    }

    const float ls = l_run + __shfl_xor(l_run, 32);
    const float inv = 1.f / ls;
    const size_t rowO = (size_t)(b*T_SEQ + qg)*DM + h*DKH;
    #pragma unroll
    for (int d = 0; d < 2; ++d){
      const f32x16& Aq = d ? acc1 : acc0;
      #pragma unroll
      for (int bb = 0; bb < 4; ++bb){
        unsigned u0 = (unsigned)f2bfc(Aq[4*bb+0]*inv) | ((unsigned)f2bfc(Aq[4*bb+1]*inv) << 16);
        unsigned u1 = (unsigned)f2bfc(Aq[4*bb+2]*inv) | ((unsigned)f2bfc(Aq[4*bb+3]*inv) << 16);
        uint2 uv; uv.x = u0; uv.y = u1;
        *(uint2*)(Og + rowO + 32*d + 8*bb + 4*h1) = uv;
      }
    }
  }
#undef ROUND
}

// ---------------- launch ----------------
extern "C" void kernel_launch(void* const* d_in, const int* in_sizes, int n_in,
                              void* d_out, int out_size, void* d_ws, size_t ws_size,
                              hipStream_t stream)
{
  (void)in_sizes; (void)n_in; (void)out_size; (void)ws_size;
  const float* H  = (const float*)d_in[0];
  const float* Wq = (const float*)d_in[1];
  const float* Wk = (const float*)d_in[2];
  const float* Wv = (const float*)d_in[3];
  const float* Wo = (const float*)d_in[4];
  char* ws = (char*)d_ws;
  unsigned short* Hb   = (unsigned short*)(ws);
  unsigned short* Wqkt = (unsigned short*)(ws + 16777216);   // rows 0-1023: Wq^T (scaled), 1024-2047: Wk^T
  unsigned short* Wkt  = (unsigned short*)(ws + 18874368);
  unsigned short* Wvt  = (unsigned short*)(ws + 20971520);
  unsigned short* Wot  = (unsigned short*)(ws + 23068672);
  unsigned short* QKb  = (unsigned short*)(ws + 25165824);   // 32MB
  unsigned short* Vtb  = (unsigned short*)(ws + 58720256);
  unsigned short* Ab   = (unsigned short*)(ws + 75497472);

  convprep<<<6144, 256, 0, stream>>>(H, Wq, Wk, Wv, Wo,
                                     (u16x4*)Hb, Wqkt, Wkt, Wvt, Wot);
  gemm_qk8<<<256, 512, 0, stream>>>(Hb, Wqkt, QKb);
  gemm_vt<<<dim3(8,64), 256, 0, stream>>>(Wvt, Hb, Vtb);
  attn_kernel<<<dim3(256), 512, 0, stream>>>(QKb, Vtb, Ab);
  gemm_out<<<dim3(64,8), 256, 0, stream>>>(Ab, Wot, (float*)d_out);
}